// Round 6
// baseline (371.261 us; speedup 1.0000x reference)
//
#include <hip/hip_runtime.h>

#define M_ROWS 16384
#define N_CODES 8192
#define K_DIM   256
#define NSPLIT  64        // code-tile splits (N/128)
#define CAP     16384
#define TAU     0.05f
#define RSTRIDE 8

typedef _Float16 half8 __attribute__((ext_vector_type(8)));
typedef float floatx16 __attribute__((ext_vector_type(16)));

#define GLL16(g, l) __builtin_amdgcn_global_load_lds(                         \
    (const __attribute__((address_space(1))) void*)(g),                       \
    (__attribute__((address_space(3))) void*)(l), 16, 0, 0)

#define MFMA16(a, b, c) __builtin_amdgcn_mfma_f32_32x32x16_f16(a, b, c, 0, 0, 0)
#define SCB __builtin_amdgcn_sched_barrier(0)

// ---- pack codebook into fragment-ordered fp16 h+l blobs ----
// blob per (code-tile 128, kc of 32): 8192 fp16 = [it4][pl2][ks2][lh2][rr32][j8]
__global__ void pack_cb(const float* __restrict__ in, _Float16* __restrict__ out) {
  const int t = blockIdx.x * 256 + threadIdx.x;
  const int C = t >> 5, G = t & 31;
  const int ct = C >> 7, r = C & 127, it = r >> 5, rr = r & 31;
  const int kc = G >> 2, g2 = G & 3, ks = g2 >> 1, lh = g2 & 1;
  const float* src = in + (size_t)C * K_DIM + G * 8;
  half8 hv, lv;
#pragma unroll
  for (int j = 0; j < 8; ++j) {
    const float v = src[j];
    const _Float16 h = (_Float16)v;
    hv[j] = h;
    lv[j] = (_Float16)(v - (float)h);
  }
  _Float16* blob = out + ((size_t)ct * 8 + kc) * 8192;
  const int offh = ((((it * 2 + 0) * 2 + ks) * 2 + lh) * 32 + rr) * 8;
  const int offl = ((((it * 2 + 1) * 2 + ks) * 2 + lh) * 32 + rr) * 8;
  *reinterpret_cast<half8*>(blob + offh) = hv;
  *reinterpret_cast<half8*>(blob + offl) = lv;
}

// ---- pack x into fragment-ordered fp16 h-only blobs ----
// blob per (row-tile 256, kc of 32): 8192 fp16 = [jt8][ks2][lh2][rr32][j8]
__global__ void pack_x(const float* __restrict__ in, _Float16* __restrict__ out) {
  const int t = blockIdx.x * 256 + threadIdx.x;
  const int R = t >> 5, G = t & 31;
  const int bx = R >> 8, r = R & 255, jt = r >> 5, rr = r & 31;
  const int kc = G >> 2, g2 = G & 3, ks = g2 >> 1, lh = g2 & 1;
  const float* src = in + (size_t)R * K_DIM + G * 8;
  half8 hv;
#pragma unroll
  for (int j = 0; j < 8; ++j) hv[j] = (_Float16)src[j];
  _Float16* blob = out + ((size_t)bx * 8 + kc) * 8192;
  const int off = (((jt * 2 + ks) * 2 + lh) * 32 + rr) * 8;
  *reinterpret_cast<half8*>(blob + off) = hv;
}

// ---- en2[c] = 0.5*||e_c||^2 (exact fp32); zeroes risky counter ----
__global__ void enorm_k(const float* __restrict__ cb, float* __restrict__ en2,
                        int* __restrict__ cnt) {
  if (blockIdx.x == 0 && threadIdx.x == 0) *cnt = 0;
  const int row = blockIdx.x * 4 + (threadIdx.x >> 6);
  const int lane = threadIdx.x & 63;
  const float4 v = *reinterpret_cast<const float4*>(cb + (size_t)row * K_DIM + lane * 4);
  float s = v.x * v.x + v.y * v.y + v.z * v.z + v.w * v.w;
#pragma unroll
  for (int o = 32; o > 0; o >>= 1) s += __shfl_down(s, o, 64);
  if (lane == 0) en2[row] = 0.5f * s;
}

// ---- fused 2-product split-f16 MFMA distance, 128 codes x 256 rows / block ----
#define STAGE(buf, kcv)                                                     \
  {                                                                         \
    const _Float16* ga_ = gA + (size_t)(kcv) * 8192;                        \
    const _Float16* gb_ = gB + (size_t)(kcv) * 8192;                        \
    _Pragma("unroll")                                                       \
    for (int q = 0; q < 4; ++q)                                             \
      GLL16(ga_ + q * 2048 + tid * 8, ldsA + (buf) * 8192 + q * 2048 + tid * 8); \
    _Pragma("unroll")                                                       \
    for (int q = 0; q < 4; ++q)                                             \
      GLL16(gb_ + q * 2048 + tid * 8, ldsB + (buf) * 8192 + q * 2048 + tid * 8); \
  }

__global__ __launch_bounds__(256, 2)
void vq_dist(const _Float16* __restrict__ Apack, const _Float16* __restrict__ Bpack,
             const float* __restrict__ en2, float* __restrict__ candV,
             int* __restrict__ candI, float* __restrict__ cand2) {
  __shared__ _Float16 ldsA[2 * 8192];   // 32KB dbuf A (codes, h+l)
  __shared__ _Float16 ldsB[2 * 8192];   // 32KB dbuf B (x rows, h)

  const int tid = threadIdx.x;
  const int wv = tid >> 6, lane = tid & 63;
  const int wm = wv >> 1, wn = wv & 1;
  const int l31 = lane & 31, lh = lane >> 5;

  // hierarchical XCD swizzle: each XCD runs 8 super-tiles of (8ct x 8bx)
  const int lid = blockIdx.x;            // 0..4095
  const int xcd = lid & 7;
  const int w = lid >> 3;                // 0..511
  const int bxl = w & 7, ctl = (w >> 3) & 7, s = w >> 6;   // s: 0..7
  const int sup = xcd + 8 * s;           // 0..63 super-tile id
  const int bx = (sup & 7) * 8 + bxl;    // 0..63
  const int ct = (sup >> 3) * 8 + ctl;   // 0..63

  const _Float16* gA = Apack + (size_t)ct * 8 * 8192;
  const _Float16* gB = Bpack + (size_t)bx * 8 * 8192;

  floatx16 acc[2][4] = {};

  STAGE(0, 0);

#pragma unroll
  for (int kc = 0; kc < 8; ++kc) {
    const int bo = (kc & 1) * 8192;
    if (kc < 7) {
      STAGE((kc + 1) & 1, kc + 1);
      asm volatile("s_waitcnt vmcnt(8)" ::: "memory");   // prev iter's 8 loads landed
    } else {
      asm volatile("s_waitcnt vmcnt(0)" ::: "memory");
    }
    SCB;
    __builtin_amdgcn_s_barrier();   // all waves' current-buffer loads landed
    SCB;

    half8 ah[2][2], al[2][2], bh[4][2];
#pragma unroll
    for (int i = 0; i < 2; ++i) {
      const int it = wm * 2 + i;
#pragma unroll
      for (int ks = 0; ks < 2; ++ks) {
        ah[i][ks] = *reinterpret_cast<const half8*>(
            ldsA + bo + ((((it * 2 + 0) * 2 + ks) * 2 + lh) * 32 + l31) * 8);
        al[i][ks] = *reinterpret_cast<const half8*>(
            ldsA + bo + ((((it * 2 + 1) * 2 + ks) * 2 + lh) * 32 + l31) * 8);
      }
    }
#pragma unroll
    for (int j = 0; j < 4; ++j) {
      const int jt = wn * 4 + j;
#pragma unroll
      for (int ks = 0; ks < 2; ++ks)
        bh[j][ks] = *reinterpret_cast<const half8*>(
            ldsB + bo + (((jt * 2 + ks) * 2 + lh) * 32 + l31) * 8);
    }
    asm volatile("s_waitcnt lgkmcnt(0)" ::: "memory");
    SCB;
    __builtin_amdgcn_s_setprio(1);
#pragma unroll
    for (int ks = 0; ks < 2; ++ks)
#pragma unroll
      for (int i = 0; i < 2; ++i)
#pragma unroll
        for (int j = 0; j < 4; ++j) {
          acc[i][j] = MFMA16(ah[i][ks], bh[j][ks], acc[i][j]);
          acc[i][j] = MFMA16(al[i][ks], bh[j][ks], acc[i][j]);
        }
    __builtin_amdgcn_s_setprio(0);
    SCB;
    __builtin_amdgcn_s_barrier();   // all waves done reading this buffer
    SCB;
  }

  // epilogue: scores + per-lane top-2 over this block's 128 codes
  float b1[4] = {-3.0e38f, -3.0e38f, -3.0e38f, -3.0e38f};
  float b2[4] = {-3.0e38f, -3.0e38f, -3.0e38f, -3.0e38f};
  int idx1[4] = {0, 0, 0, 0};
#pragma unroll
  for (int i = 0; i < 2; ++i) {
    const int code0 = ct * 128 + (wm * 2 + i) * 32;
    const float* ep = en2 + code0 + 4 * lh;
    const float4 e0 = *reinterpret_cast<const float4*>(ep);
    const float4 e1 = *reinterpret_cast<const float4*>(ep + 8);
    const float4 e2 = *reinterpret_cast<const float4*>(ep + 16);
    const float4 e3 = *reinterpret_cast<const float4*>(ep + 24);
    const float ev[16] = {e0.x, e0.y, e0.z, e0.w, e1.x, e1.y, e1.z, e1.w,
                          e2.x, e2.y, e2.z, e2.w, e3.x, e3.y, e3.z, e3.w};
#pragma unroll
    for (int reg = 0; reg < 16; ++reg) {
      const int code = code0 + (reg & 3) + 8 * (reg >> 2) + 4 * lh;
#pragma unroll
      for (int j = 0; j < 4; ++j) {
        const float v = acc[i][j][reg] - ev[reg];
        if (v > b1[j] || (v == b1[j] && code < idx1[j])) {
          b2[j] = b1[j]; b1[j] = v; idx1[j] = code;
        } else if (v > b2[j]) {
          b2[j] = v;
        }
      }
    }
  }

  // merge lane <-> lane^32 (same x-row, disjoint code subsets)
#pragma unroll
  for (int j = 0; j < 4; ++j) {
    const float o1 = __shfl_xor(b1[j], 32, 64);
    const int oi = __shfl_xor(idx1[j], 32, 64);
    const float o2 = __shfl_xor(b2[j], 32, 64);
    const bool win = (b1[j] > o1) || (b1[j] == o1 && idx1[j] < oi);
    const float lose1 = win ? o1 : b1[j];
    b1[j] = win ? b1[j] : o1;
    idx1[j] = win ? idx1[j] : oi;
    b2[j] = fmaxf(fmaxf(b2[j], o2), lose1);
  }

  // cross-wave (wm 0 vs 1) merge via LDS scratch
  float* scr = reinterpret_cast<float*>(ldsA);   // [2][256][3] = 6KB
  __syncthreads();
  if (lane < 32) {
#pragma unroll
    for (int j = 0; j < 4; ++j) {
      const int rowl = (wn * 4 + j) * 32 + l31;
      const int base = (wm * 256 + rowl) * 3;
      scr[base + 0] = b1[j];
      scr[base + 1] = __int_as_float(idx1[j]);
      scr[base + 2] = b2[j];
    }
  }
  __syncthreads();
  {
    float v1 = scr[tid * 3 + 0];
    int ii = __float_as_int(scr[tid * 3 + 1]);
    float v2 = scr[tid * 3 + 2];
    const float o1 = scr[(256 + tid) * 3 + 0];
    const int oi = __float_as_int(scr[(256 + tid) * 3 + 1]);
    const float o2 = scr[(256 + tid) * 3 + 2];
    const bool win = (v1 > o1) || (v1 == o1 && ii < oi);
    const float lose1 = win ? o1 : v1;
    const float nb1 = win ? v1 : o1;
    const int ni = win ? ii : oi;
    const float nb2 = fmaxf(fmaxf(v2, o2), lose1);
    const int row = bx * 256 + tid;
    // transposed [ct][row] layout: fully coalesced
    candV[(size_t)ct * M_ROWS + row] = nb1;
    candI[(size_t)ct * M_ROWS + row] = ni;
    cand2[(size_t)ct * M_ROWS + row] = nb2;
  }
}

// ---- merge splits -> index, margin; flag risky rows (coalesced reads) ----
__global__ void vq_reduce(const float* __restrict__ candV, const int* __restrict__ candI,
                          const float* __restrict__ cand2, int* __restrict__ ind,
                          int* __restrict__ cnt, int* __restrict__ risky,
                          unsigned long long* __restrict__ key) {
  const int row = blockIdx.x * blockDim.x + threadIdx.x;
  if (row >= M_ROWS) return;
  float b1 = candV[row];
  int i1 = candI[row];
  float b2 = cand2[row];
  for (int s = 1; s < NSPLIT; ++s) {
    const float v = candV[(size_t)s * M_ROWS + row];
    const int ii = candI[(size_t)s * M_ROWS + row];
    const float v2 = cand2[(size_t)s * M_ROWS + row];
    if (v > b1 || (v == b1 && ii < i1)) {
      b2 = fmaxf(b1, v2); b1 = v; i1 = ii;
    } else {
      b2 = fmaxf(b2, v);
    }
  }
  ind[row] = i1;
  if (b1 - b2 < TAU) {
    const int p = atomicAdd(cnt, 1);
    if (p < CAP) { risky[p] = row; key[row] = 0ull; }
  }
}

// ---- exact fp32 rescore of risky rows, striped over RSTRIDE block-columns ----
__global__ __launch_bounds__(256)
void vq_refine(const float* __restrict__ x, const float* __restrict__ cb,
               const float* __restrict__ en2, const int* __restrict__ cnt,
               const int* __restrict__ risky, unsigned long long* __restrict__ key) {
  __shared__ float cbs[16][256];
  __shared__ float xs[256];
  const int n0 = *cnt;
  const int n = n0 < CAP ? n0 : CAP;
  const int stripe = blockIdx.x;
  if (stripe >= n) return;
  const int tid = threadIdx.x;
  const int cBase = blockIdx.y * 16;
#pragma unroll
  for (int q = 0; q < 16; ++q) cbs[q][tid] = cb[(size_t)(cBase + q) * K_DIM + tid];
  const int sub = tid & 15;
  const int cl = tid >> 4;
  for (int t = stripe; t < n; t += RSTRIDE) {
    const int row = risky[t];
    __syncthreads();
    xs[tid] = x[(size_t)row * K_DIM + tid];
    __syncthreads();
    float s = 0.f;
#pragma unroll
    for (int k = 0; k < 16; ++k) s = fmaf(xs[sub * 16 + k], cbs[cl][sub * 16 + k], s);
    s += __shfl_xor(s, 1, 64); s += __shfl_xor(s, 2, 64);
    s += __shfl_xor(s, 4, 64); s += __shfl_xor(s, 8, 64);
    if (sub == 0) {
      const int code = cBase + cl;
      const float sc = s - en2[code];
      unsigned u = __float_as_uint(sc);
      u ^= (u >> 31) ? 0xFFFFFFFFu : 0x80000000u;
      const unsigned long long k64 =
          ((unsigned long long)u << 32) | (unsigned)(N_CODES - 1 - code);
      atomicMax(key + row, k64);
    }
  }
}

__global__ void vq_fix(const int* __restrict__ cnt, const int* __restrict__ risky,
                       const unsigned long long* __restrict__ key, int* __restrict__ ind) {
  const int i = blockIdx.x * blockDim.x + threadIdx.x;
  const int n = *cnt < CAP ? *cnt : CAP;
  if (i < n) {
    const int r = risky[i];
    ind[r] = N_CODES - 1 - (int)(unsigned)(key[r] & 0xFFFFFFFFull);
  }
}

// ---- gather z_q, write z_q_st + indices, partial loss sums ----
__global__ void vq_gather(const float* __restrict__ x, const float* __restrict__ cb,
                          const int* __restrict__ ind, float* __restrict__ zq,
                          float* __restrict__ idxf, float* __restrict__ partial) {
  __shared__ float red[256];
  const int g = blockIdx.x * 256 + threadIdx.x;
  const int row = g >> 6;
  const int c4 = g & 63;
  const int idx = ind[row];
  if (c4 == 0) idxf[row] = (float)idx;
  const float4 z = *reinterpret_cast<const float4*>(cb + (size_t)idx * K_DIM + c4 * 4);
  const float4 xv = *reinterpret_cast<const float4*>(x + (size_t)g * 4);
  *reinterpret_cast<float4*>(zq + (size_t)g * 4) = z;
  const float dx = z.x - xv.x, dy = z.y - xv.y, dz = z.z - xv.z, dw = z.w - xv.w;
  red[threadIdx.x] = dx * dx + dy * dy + dz * dz + dw * dw;
  __syncthreads();
  for (int o = 128; o > 0; o >>= 1) {
    if (threadIdx.x < o) red[threadIdx.x] += red[threadIdx.x + o];
    __syncthreads();
  }
  if (threadIdx.x == 0) partial[blockIdx.x] = red[0];
}

__global__ void vq_loss(const float* __restrict__ partial, float* __restrict__ out) {
  __shared__ float red[256];
  float s = 0.f;
  for (int i = threadIdx.x; i < 4096; i += 256) s += partial[i];
  red[threadIdx.x] = s;
  __syncthreads();
  for (int o = 128; o > 0; o >>= 1) {
    if (threadIdx.x < o) red[threadIdx.x] += red[threadIdx.x + o];
    __syncthreads();
  }
  if (threadIdx.x == 0) out[0] = 1.25f * red[0] / 4194304.0f;
}

extern "C" void kernel_launch(void* const* d_in, const int* in_sizes, int n_in,
                              void* d_out, int out_size, void* d_ws, size_t ws_size,
                              hipStream_t stream) {
  const float* x = (const float*)d_in[0];
  const float* cb = (const float*)d_in[1];
  float* out = (float*)d_out;
  float* zq = out;
  float* loss = out + 4194304;
  float* idxf = out + 4194305;

  char* w = (char*)d_ws;
  _Float16* Apack = (_Float16*)w;                      w += (size_t)N_CODES * K_DIM * 2 * 2;   // 8MB h+l
  _Float16* Bpack = (_Float16*)w;                      w += (size_t)M_ROWS * K_DIM * 2;        // 8MB h
  unsigned long long* key = (unsigned long long*)w;    w += (size_t)M_ROWS * 8;
  float* en2 = (float*)w;                              w += (size_t)N_CODES * 4;
  float* candV = (float*)w;                            w += (size_t)M_ROWS * NSPLIT * 4;
  float* cand2 = (float*)w;                            w += (size_t)M_ROWS * NSPLIT * 4;
  int* candI = (int*)w;                                w += (size_t)M_ROWS * NSPLIT * 4;
  int* ind = (int*)w;                                  w += (size_t)M_ROWS * 4;
  int* risky = (int*)w;                                w += (size_t)CAP * 4;
  int* cnt = (int*)w;                                  w += 64;
  float* part = (float*)w;                             w += 4096 * 4;

  pack_cb<<<(N_CODES * 32) / 256, 256, 0, stream>>>(cb, Apack);
  pack_x<<<(M_ROWS * 32) / 256, 256, 0, stream>>>(x, Bpack);
  enorm_k<<<N_CODES / 4, 256, 0, stream>>>(cb, en2, cnt);
  vq_dist<<<4096, 256, 0, stream>>>(Apack, Bpack, en2, candV, candI, cand2);
  vq_reduce<<<M_ROWS / 256, 256, 0, stream>>>(candV, candI, cand2, ind, cnt, risky, key);
  vq_refine<<<dim3(RSTRIDE, N_CODES / 16), 256, 0, stream>>>(x, cb, en2, cnt, risky, key);
  vq_fix<<<CAP / 256, 256, 0, stream>>>(cnt, risky, key, ind);
  vq_gather<<<4194304 / (256 * 4), 256, 0, stream>>>(x, cb, ind, zq, idxf, part);
  vq_loss<<<1, 256, 0, stream>>>(part, loss);
}

// Round 7
// 327.265 us; speedup vs baseline: 1.1344x; 1.1344x over previous
//
#include <hip/hip_runtime.h>

#define M_ROWS 16384
#define N_CODES 8192
#define K_DIM   256
#define NSPLIT  64        // code-tile splits (N/128)
#define CAP     16384
#define TAU     0.05f
#define RSTRIDE 8

typedef _Float16 half8 __attribute__((ext_vector_type(8)));
typedef float floatx16 __attribute__((ext_vector_type(16)));

#define GLL16(g, l) __builtin_amdgcn_global_load_lds(                         \
    (const __attribute__((address_space(1))) void*)(g),                       \
    (__attribute__((address_space(3))) void*)(l), 16, 0, 0)

#define MFMA16(a, b, c) __builtin_amdgcn_mfma_f32_32x32x16_f16(a, b, c, 0, 0, 0)
#define SCB __builtin_amdgcn_sched_barrier(0)

// ---- fused pack: codebook(h+l)+en2, x(h), cnt zero -- one launch ----
// A blob per (ct of 128 codes, kc of 32): 16KB = [ks2][pl2][it4][lh2][rr32][j8]
// B blob per (bx of 256 rows, kc of 32): 16KB = [ks2][jt8][lh2][rr32][j8]
__global__ void pack_all(const float* __restrict__ x, const float* __restrict__ cb,
                         _Float16* __restrict__ Apack, _Float16* __restrict__ Bpack,
                         float* __restrict__ en2, int* __restrict__ cnt) {
  const int bid = blockIdx.x;
  const int tid = threadIdx.x;
  if (bid == 0 && tid == 0) *cnt = 0;
  if (bid < 1024) {
    const int t = bid * 256 + tid;
    const int C = t >> 5, G = t & 31;
    const int ct = C >> 7, r = C & 127, it = r >> 5, rr = r & 31;
    const int kc = G >> 2, g2 = G & 3, ks = g2 >> 1, lh = g2 & 1;
    const float* src = cb + (size_t)C * K_DIM + G * 8;
    half8 hv, lv;
    float ss = 0.f;
#pragma unroll
    for (int j = 0; j < 8; ++j) {
      const float v = src[j];
      const _Float16 h = (_Float16)v;
      hv[j] = h;
      lv[j] = (_Float16)(v - (float)h);
      ss += v * v;
    }
    ss += __shfl_xor(ss, 1, 32); ss += __shfl_xor(ss, 2, 32);
    ss += __shfl_xor(ss, 4, 32); ss += __shfl_xor(ss, 8, 32);
    ss += __shfl_xor(ss, 16, 32);
    if (G == 0) en2[C] = 0.5f * ss;
    _Float16* blob = Apack + ((size_t)ct * 8 + kc) * 8192;
    const int offh = ((((ks * 2 + 0) * 4 + it) * 2 + lh) * 32 + rr) * 8;
    const int offl = ((((ks * 2 + 1) * 4 + it) * 2 + lh) * 32 + rr) * 8;
    *reinterpret_cast<half8*>(blob + offh) = hv;
    *reinterpret_cast<half8*>(blob + offl) = lv;
  } else {
    const int t = (bid - 1024) * 256 + tid;
    const int R = t >> 5, G = t & 31;
    const int bx = R >> 8, r = R & 255, jt = r >> 5, rr = r & 31;
    const int kc = G >> 2, g2 = G & 3, ks = g2 >> 1, lh = g2 & 1;
    const float* src = x + (size_t)R * K_DIM + G * 8;
    half8 hv;
#pragma unroll
    for (int j = 0; j < 8; ++j) hv[j] = (_Float16)src[j];
    _Float16* blob = Bpack + ((size_t)bx * 8 + kc) * 8192;
    const int off = (((ks * 8 + jt) * 2 + lh) * 32 + rr) * 8;
    *reinterpret_cast<half8*>(blob + off) = hv;
  }
}

// ---- fused 2-product split-f16 MFMA distance ----
// block: 128 codes x 256 rows, 4 waves (2 wm x 2 wn), per-wave 64x128.
// true counted pipeline: 2 phases/kc, vmcnt(8) gate BEFORE the reads it protects.
__global__ __launch_bounds__(256, 2)
void vq_dist(const _Float16* __restrict__ Apack, const _Float16* __restrict__ Bpack,
             const float* __restrict__ en2, float* __restrict__ candV,
             int* __restrict__ candI, float* __restrict__ cand2) {
  __shared__ _Float16 ldsA[2 * 8192];   // 32KB dbuf A kc-chunks (h+l)
  __shared__ _Float16 ldsB[2 * 8192];   // 32KB dbuf B kc-chunks (h)

  const int tid = threadIdx.x;
  const int wv = tid >> 6, lane = tid & 63;
  const int wm = wv >> 1, wn = wv & 1;
  const int l31 = lane & 31, lh = lane >> 5;

  // hierarchical XCD swizzle: 8 super-tiles of (8ct x 8bx) per XCD
  const int lid = blockIdx.x;            // 0..4095
  const int xcd = lid & 7;
  const int w = lid >> 3;
  const int bxl = w & 7, ctl = (w >> 3) & 7, s = w >> 6;
  const int sup = xcd + 8 * s;
  const int bx = (sup & 7) * 8 + bxl;    // 0..63
  const int ct = (sup >> 3) * 8 + ctl;   // 0..63

  const _Float16* gA = Apack + (size_t)ct * 8 * 8192;
  const _Float16* gB = Bpack + (size_t)bx * 8 * 8192;

  floatx16 acc[2][4] = {};

  // prologue: stage kc=0, half0 then half1 (order matters for vmcnt counting)
#pragma unroll
  for (int h = 0; h < 2; ++h) {
#pragma unroll
    for (int q = 0; q < 2; ++q)
      GLL16(gA + h * 4096 + (wv * 2 + q) * 512 + lane * 8,
            ldsA + h * 4096 + (wv * 2 + q) * 512);
#pragma unroll
    for (int q = 0; q < 2; ++q)
      GLL16(gB + h * 4096 + (wv * 2 + q) * 512 + lane * 8,
            ldsB + h * 4096 + (wv * 2 + q) * 512);
    SCB;   // keep h0 group strictly before h1 group
  }

  for (int kc = 0; kc < 8; ++kc) {
    const int bo = (kc & 1) * 8192;
    const int nbo = bo ^ 8192;
    const _Float16* gaN = gA + (size_t)(kc + 1) * 8192;
    const _Float16* gbN = gB + (size_t)(kc + 1) * 8192;

#pragma unroll
    for (int h = 0; h < 2; ++h) {
      // 1) issue next-kc half-h staging (never mid-loop drained)
      if (kc < 7) {
#pragma unroll
        for (int q = 0; q < 2; ++q)
          GLL16(gaN + h * 4096 + (wv * 2 + q) * 512 + lane * 8,
                ldsA + nbo + h * 4096 + (wv * 2 + q) * 512);
#pragma unroll
        for (int q = 0; q < 2; ++q)
          GLL16(gbN + h * 4096 + (wv * 2 + q) * 512 + lane * 8,
                ldsB + nbo + h * 4096 + (wv * 2 + q) * 512);
      }
      // 2) counted gate for (kc,h): those 4 loads were issued 2 phases ago
      if (kc < 7) {
        asm volatile("s_waitcnt vmcnt(8)" ::: "memory");
      } else if (h == 0) {
        asm volatile("s_waitcnt vmcnt(4)" ::: "memory");
      } else {
        asm volatile("s_waitcnt vmcnt(0)" ::: "memory");
      }
      SCB;
      __builtin_amdgcn_s_barrier();   // all waves' quarter-sections landed
      SCB;
      // 3) fragment reads for (kc, ks=h)
      half8 ah[2], al[2], bh[4];
#pragma unroll
      for (int i = 0; i < 2; ++i) {
        const int it = wm * 2 + i;
        ah[i] = *reinterpret_cast<const half8*>(
            ldsA + bo + (((h * 2 + 0) * 4 + it) * 2 + lh) * 256 + l31 * 8);
        al[i] = *reinterpret_cast<const half8*>(
            ldsA + bo + (((h * 2 + 1) * 4 + it) * 2 + lh) * 256 + l31 * 8);
      }
#pragma unroll
      for (int j = 0; j < 4; ++j) {
        const int jt = wn * 4 + j;
        bh[j] = *reinterpret_cast<const half8*>(
            ldsB + bo + ((h * 8 + jt) * 2 + lh) * 256 + l31 * 8);
      }
      asm volatile("s_waitcnt lgkmcnt(0)" ::: "memory");
      SCB;
      // 4) 16 MFMA
      __builtin_amdgcn_s_setprio(1);
#pragma unroll
      for (int i = 0; i < 2; ++i)
#pragma unroll
        for (int j = 0; j < 4; ++j) {
          acc[i][j] = MFMA16(ah[i], bh[j], acc[i][j]);
          acc[i][j] = MFMA16(al[i], bh[j], acc[i][j]);
        }
      __builtin_amdgcn_s_setprio(0);
      SCB;
    }
  }

  // epilogue: scores + per-lane top-2 over this block's 128 codes
  float b1[4] = {-3.0e38f, -3.0e38f, -3.0e38f, -3.0e38f};
  float b2[4] = {-3.0e38f, -3.0e38f, -3.0e38f, -3.0e38f};
  int idx1[4] = {0, 0, 0, 0};
#pragma unroll
  for (int i = 0; i < 2; ++i) {
    const int code0 = ct * 128 + wm * 64 + i * 32;
    const float* ep = en2 + code0 + 4 * lh;
    const float4 e0 = *reinterpret_cast<const float4*>(ep);
    const float4 e1 = *reinterpret_cast<const float4*>(ep + 8);
    const float4 e2 = *reinterpret_cast<const float4*>(ep + 16);
    const float4 e3 = *reinterpret_cast<const float4*>(ep + 24);
    const float ev[16] = {e0.x, e0.y, e0.z, e0.w, e1.x, e1.y, e1.z, e1.w,
                          e2.x, e2.y, e2.z, e2.w, e3.x, e3.y, e3.z, e3.w};
#pragma unroll
    for (int reg = 0; reg < 16; ++reg) {
      const int code = code0 + (reg & 3) + 8 * (reg >> 2) + 4 * lh;
#pragma unroll
      for (int j = 0; j < 4; ++j) {
        const float v = acc[i][j][reg] - ev[reg];
        if (v > b1[j] || (v == b1[j] && code < idx1[j])) {
          b2[j] = b1[j]; b1[j] = v; idx1[j] = code;
        } else if (v > b2[j]) {
          b2[j] = v;
        }
      }
    }
  }

  // merge lane <-> lane^32 (same x-row, disjoint code subsets)
#pragma unroll
  for (int j = 0; j < 4; ++j) {
    const float o1 = __shfl_xor(b1[j], 32, 64);
    const int oi = __shfl_xor(idx1[j], 32, 64);
    const float o2 = __shfl_xor(b2[j], 32, 64);
    const bool win = (b1[j] > o1) || (b1[j] == o1 && idx1[j] < oi);
    const float lose1 = win ? o1 : b1[j];
    b1[j] = win ? b1[j] : o1;
    idx1[j] = win ? idx1[j] : oi;
    b2[j] = fmaxf(fmaxf(b2[j], o2), lose1);
  }

  // cross-wave (wm 0 vs 1) merge via LDS scratch
  float* scr = reinterpret_cast<float*>(ldsA);   // [2][256][3]
  __syncthreads();
  if (lane < 32) {
#pragma unroll
    for (int j = 0; j < 4; ++j) {
      const int rowl = wn * 128 + j * 32 + l31;
      const int base = (wm * 256 + rowl) * 3;
      scr[base + 0] = b1[j];
      scr[base + 1] = __int_as_float(idx1[j]);
      scr[base + 2] = b2[j];
    }
  }
  __syncthreads();
  {
    float v1 = scr[tid * 3 + 0];
    int ii = __float_as_int(scr[tid * 3 + 1]);
    float v2 = scr[tid * 3 + 2];
    const float o1 = scr[(256 + tid) * 3 + 0];
    const int oi = __float_as_int(scr[(256 + tid) * 3 + 1]);
    const float o2 = scr[(256 + tid) * 3 + 2];
    const bool win = (v1 > o1) || (v1 == o1 && ii < oi);
    const float lose1 = win ? o1 : v1;
    const float nb1 = win ? v1 : o1;
    const int ni = win ? ii : oi;
    const float nb2 = fmaxf(fmaxf(v2, o2), lose1);
    const int row = bx * 256 + tid;
    candV[(size_t)ct * M_ROWS + row] = nb1;
    candI[(size_t)ct * M_ROWS + row] = ni;
    cand2[(size_t)ct * M_ROWS + row] = nb2;
  }
}

// ---- merge splits -> index, margin; flag risky (256 blocks, coalesced) ----
__global__ void vq_reduce(const float* __restrict__ candV, const int* __restrict__ candI,
                          const float* __restrict__ cand2, int* __restrict__ ind,
                          int* __restrict__ cnt, int* __restrict__ risky,
                          unsigned long long* __restrict__ key) {
  __shared__ float sv[4][64], s2[4][64];
  __shared__ int si[4][64];
  const int tid = threadIdx.x;
  const int c = tid >> 6, r = tid & 63;
  const int row = blockIdx.x * 64 + r;
  float b1 = -3.0e38f, b2 = -3.0e38f;
  int i1 = 0;
#pragma unroll
  for (int q = 0; q < 16; ++q) {
    const int sp = c * 16 + q;
    const float v = candV[(size_t)sp * M_ROWS + row];
    const int ii = candI[(size_t)sp * M_ROWS + row];
    const float v2 = cand2[(size_t)sp * M_ROWS + row];
    if (v > b1 || (v == b1 && ii < i1)) {
      b2 = fmaxf(b1, v2); b1 = v; i1 = ii;
    } else {
      b2 = fmaxf(b2, v);
    }
  }
  sv[c][r] = b1; si[c][r] = i1; s2[c][r] = b2;
  __syncthreads();
  if (tid < 64) {
    float nb1 = sv[0][tid]; int ni = si[0][tid]; float nb2 = s2[0][tid];
#pragma unroll
    for (int cc = 1; cc < 4; ++cc) {
      const float v = sv[cc][tid];
      const int ii = si[cc][tid];
      const float v2 = s2[cc][tid];
      if (v > nb1 || (v == nb1 && ii < ni)) {
        nb2 = fmaxf(nb1, v2); nb1 = v; ni = ii;
      } else {
        nb2 = fmaxf(nb2, v);
      }
    }
    const int rr = blockIdx.x * 64 + tid;
    ind[rr] = ni;
    if (nb1 - nb2 < TAU) {
      const int p = atomicAdd(cnt, 1);
      if (p < CAP) { risky[p] = rr; key[rr] = 0ull; }
    }
  }
}

// ---- exact fp32 rescore of risky rows; block pre-reduce -> 1 atomic ----
__global__ __launch_bounds__(256)
void vq_refine(const float* __restrict__ x, const float* __restrict__ cb,
               const float* __restrict__ en2, const int* __restrict__ cnt,
               const int* __restrict__ risky, unsigned long long* __restrict__ key) {
  __shared__ float cbs[16][256];
  __shared__ float xs[256];
  __shared__ float scS[16];
  const int n0 = *cnt;
  const int n = n0 < CAP ? n0 : CAP;
  const int stripe = blockIdx.x;
  if (stripe >= n) return;
  const int tid = threadIdx.x;
  const int cBase = blockIdx.y * 16;
#pragma unroll
  for (int q = 0; q < 16; ++q) cbs[q][tid] = cb[(size_t)(cBase + q) * K_DIM + tid];
  const int sub = tid & 15;
  const int cl = tid >> 4;
  const float e_c = en2[cBase + cl];
  for (int t = stripe; t < n; t += RSTRIDE) {
    const int row = risky[t];
    __syncthreads();
    xs[tid] = x[(size_t)row * K_DIM + tid];
    __syncthreads();
    float s = 0.f;
#pragma unroll
    for (int k = 0; k < 16; ++k) s = fmaf(xs[sub * 16 + k], cbs[cl][sub * 16 + k], s);
    s += __shfl_xor(s, 1, 64); s += __shfl_xor(s, 2, 64);
    s += __shfl_xor(s, 4, 64); s += __shfl_xor(s, 8, 64);
    if (sub == 0) scS[cl] = s - e_c;
    __syncthreads();
    if (tid == 0) {
      float bb = scS[0]; int bc = cBase;
#pragma unroll
      for (int q = 1; q < 16; ++q) {
        if (scS[q] > bb) { bb = scS[q]; bc = cBase + q; }
      }
      unsigned u = __float_as_uint(bb);
      u ^= (u >> 31) ? 0xFFFFFFFFu : 0x80000000u;
      const unsigned long long k64 =
          ((unsigned long long)u << 32) | (unsigned)(N_CODES - 1 - bc);
      atomicMax(key + row, k64);
    }
  }
}

__global__ void vq_fix(const int* __restrict__ cnt, const int* __restrict__ risky,
                       const unsigned long long* __restrict__ key, int* __restrict__ ind) {
  const int i = blockIdx.x * blockDim.x + threadIdx.x;
  const int n = *cnt < CAP ? *cnt : CAP;
  if (i < n) {
    const int r = risky[i];
    ind[r] = N_CODES - 1 - (int)(unsigned)(key[r] & 0xFFFFFFFFull);
  }
}

// ---- gather z_q, write z_q_st + indices, partial loss sums ----
__global__ void vq_gather(const float* __restrict__ x, const float* __restrict__ cb,
                          const int* __restrict__ ind, float* __restrict__ zq,
                          float* __restrict__ idxf, float* __restrict__ partial) {
  __shared__ float red[256];
  const int g = blockIdx.x * 256 + threadIdx.x;
  const int row = g >> 6;
  const int c4 = g & 63;
  const int idx = ind[row];
  if (c4 == 0) idxf[row] = (float)idx;
  const float4 z = *reinterpret_cast<const float4*>(cb + (size_t)idx * K_DIM + c4 * 4);
  const float4 xv = *reinterpret_cast<const float4*>(x + (size_t)g * 4);
  *reinterpret_cast<float4*>(zq + (size_t)g * 4) = z;
  const float dx = z.x - xv.x, dy = z.y - xv.y, dz = z.z - xv.z, dw = z.w - xv.w;
  red[threadIdx.x] = dx * dx + dy * dy + dz * dz + dw * dw;
  __syncthreads();
  for (int o = 128; o > 0; o >>= 1) {
    if (threadIdx.x < o) red[threadIdx.x] += red[threadIdx.x + o];
    __syncthreads();
  }
  if (threadIdx.x == 0) partial[blockIdx.x] = red[0];
}

__global__ void vq_loss(const float* __restrict__ partial, float* __restrict__ out) {
  __shared__ float red[256];
  float s = 0.f;
  for (int i = threadIdx.x; i < 4096; i += 256) s += partial[i];
  red[threadIdx.x] = s;
  __syncthreads();
  for (int o = 128; o > 0; o >>= 1) {
    if (threadIdx.x < o) red[threadIdx.x] += red[threadIdx.x + o];
    __syncthreads();
  }
  if (threadIdx.x == 0) out[0] = 1.25f * red[0] / 4194304.0f;
}

extern "C" void kernel_launch(void* const* d_in, const int* in_sizes, int n_in,
                              void* d_out, int out_size, void* d_ws, size_t ws_size,
                              hipStream_t stream) {
  const float* x = (const float*)d_in[0];
  const float* cb = (const float*)d_in[1];
  float* out = (float*)d_out;
  float* zq = out;
  float* loss = out + 4194304;
  float* idxf = out + 4194305;

  char* w = (char*)d_ws;
  _Float16* Apack = (_Float16*)w;                      w += (size_t)N_CODES * K_DIM * 2 * 2;   // 8MB h+l
  _Float16* Bpack = (_Float16*)w;                      w += (size_t)M_ROWS * K_DIM * 2;        // 8MB h
  unsigned long long* key = (unsigned long long*)w;    w += (size_t)M_ROWS * 8;
  float* en2 = (float*)w;                              w += (size_t)N_CODES * 4;
  float* candV = (float*)w;                            w += (size_t)M_ROWS * NSPLIT * 4;
  float* cand2 = (float*)w;                            w += (size_t)M_ROWS * NSPLIT * 4;
  int* candI = (int*)w;                                w += (size_t)M_ROWS * NSPLIT * 4;
  int* ind = (int*)w;                                  w += (size_t)M_ROWS * 4;
  int* risky = (int*)w;                                w += (size_t)CAP * 4;
  int* cnt = (int*)w;                                  w += 64;
  float* part = (float*)w;                             w += 4096 * 4;

  pack_all<<<3072, 256, 0, stream>>>(x, cb, Apack, Bpack, en2, cnt);
  vq_dist<<<4096, 256, 0, stream>>>(Apack, Bpack, en2, candV, candI, cand2);
  vq_reduce<<<256, 256, 0, stream>>>(candV, candI, cand2, ind, cnt, risky, key);
  vq_refine<<<dim3(RSTRIDE, N_CODES / 16), 256, 0, stream>>>(x, cb, en2, cnt, risky, key);
  vq_fix<<<CAP / 256, 256, 0, stream>>>(cnt, risky, key, ind);
  vq_gather<<<4194304 / (256 * 4), 256, 0, stream>>>(x, cb, ind, zq, idxf, part);
  vq_loss<<<1, 256, 0, stream>>>(part, loss);
}

// Round 8
// 265.001 us; speedup vs baseline: 1.4010x; 1.2350x over previous
//
#include <hip/hip_runtime.h>

#define M_ROWS 16384
#define N_CODES 8192
#define K_DIM   256
#define NSPLIT  64
#define CAP     16384
#define TAU     0.05f

typedef _Float16 half8 __attribute__((ext_vector_type(8)));
typedef float floatx16 __attribute__((ext_vector_type(16)));

#define GLL16(g, l) __builtin_amdgcn_global_load_lds(                         \
    (const __attribute__((address_space(1))) void*)(g),                       \
    (__attribute__((address_space(3))) void*)(l), 16, 0, 0)

#define MFMA16(a, b, c) __builtin_amdgcn_mfma_f32_32x32x16_f16(a, b, c, 0, 0, 0)
#define SCB __builtin_amdgcn_sched_barrier(0)

// ---- fused pack: codebook(h+l)+en2, x(h), cnt zero ----
// A blob per (ct 128 codes, kc 32): [ks2][pl2][it4][lh2][rr32][j8] halfs
// B blob per (bx 256 rows, kc 32):  [ks2][jt8][lh2][rr32][j8] halfs
__global__ void pack_all(const float* __restrict__ x, const float* __restrict__ cb,
                         _Float16* __restrict__ Apack, _Float16* __restrict__ Bpack,
                         float* __restrict__ en2, int* __restrict__ cnt) {
  const int bid = blockIdx.x;
  const int tid = threadIdx.x;
  if (bid == 0 && tid == 0) *cnt = 0;
  if (bid < 1024) {
    const int t = bid * 256 + tid;
    const int C = t >> 5, G = t & 31;
    const int ct = C >> 7, r = C & 127, it = r >> 5, rr = r & 31;
    const int kc = G >> 2, g2 = G & 3, ks = g2 >> 1, lh = g2 & 1;
    const float* src = cb + (size_t)C * K_DIM + G * 8;
    half8 hv, lv;
    float ss = 0.f;
#pragma unroll
    for (int j = 0; j < 8; ++j) {
      const float v = src[j];
      const _Float16 h = (_Float16)v;
      hv[j] = h;
      lv[j] = (_Float16)(v - (float)h);
      ss += v * v;
    }
    ss += __shfl_xor(ss, 1, 32); ss += __shfl_xor(ss, 2, 32);
    ss += __shfl_xor(ss, 4, 32); ss += __shfl_xor(ss, 8, 32);
    ss += __shfl_xor(ss, 16, 32);
    if (G == 0) en2[C] = 0.5f * ss;
    _Float16* blob = Apack + ((size_t)ct * 8 + kc) * 8192;
    const int offh = ((((ks * 2 + 0) * 4 + it) * 2 + lh) * 32 + rr) * 8;
    const int offl = ((((ks * 2 + 1) * 4 + it) * 2 + lh) * 32 + rr) * 8;
    *reinterpret_cast<half8*>(blob + offh) = hv;
    *reinterpret_cast<half8*>(blob + offl) = lv;
  } else {
    const int t = (bid - 1024) * 256 + tid;
    const int R = t >> 5, G = t & 31;
    const int bx = R >> 8, r = R & 255, jt = r >> 5, rr = r & 31;
    const int kc = G >> 2, g2 = G & 3, ks = g2 >> 1, lh = g2 & 1;
    const float* src = x + (size_t)R * K_DIM + G * 8;
    half8 hv;
#pragma unroll
    for (int j = 0; j < 8; ++j) hv[j] = (_Float16)src[j];
    _Float16* blob = Bpack + ((size_t)bx * 8 + kc) * 8192;
    const int off = (((ks * 8 + jt) * 2 + lh) * 32 + rr) * 8;
    *reinterpret_cast<half8*>(blob + off) = hv;
  }
}

// ---- fused 2-product split-f16 MFMA distance ----
// block 128 codes x 256 rows, 4 waves; ks-split software pipeline per kc.
#define STAGE(bufo, kcv)                                                    \
  {                                                                         \
    const _Float16* ga_ = gA + (size_t)(kcv) * 8192;                        \
    const _Float16* gb_ = gB + (size_t)(kcv) * 8192;                        \
    _Pragma("unroll")                                                       \
    for (int q = 0; q < 4; ++q)                                             \
      GLL16(ga_ + q * 2048 + tid * 8, ldsA + (bufo) + q * 2048 + tid * 8);  \
    _Pragma("unroll")                                                       \
    for (int q = 0; q < 4; ++q)                                             \
      GLL16(gb_ + q * 2048 + tid * 8, ldsB + (bufo) + q * 2048 + tid * 8);  \
  }

__global__ __launch_bounds__(256, 2)
void vq_dist(const _Float16* __restrict__ Apack, const _Float16* __restrict__ Bpack,
             const float* __restrict__ en2, float* __restrict__ candV,
             int* __restrict__ candI, float* __restrict__ cand2) {
  __shared__ _Float16 ldsA[2 * 8192];   // 32KB dbuf A (h+l)
  __shared__ _Float16 ldsB[2 * 8192];   // 32KB dbuf B (h)

  const int tid = threadIdx.x;
  const int wv = tid >> 6, lane = tid & 63;
  const int wm = wv >> 1, wn = wv & 1;
  const int l31 = lane & 31, lh = lane >> 5;

  // hierarchical XCD swizzle: 8 super-tiles of (8ct x 8bx) per XCD
  const int lid = blockIdx.x;
  const int xcd = lid & 7;
  const int w = lid >> 3;
  const int bxl = w & 7, ctl = (w >> 3) & 7, s = w >> 6;
  const int sup = xcd + 8 * s;
  const int bx = (sup & 7) * 8 + bxl;
  const int ct = (sup >> 3) * 8 + ctl;

  const _Float16* gA = Apack + (size_t)ct * 8 * 8192;
  const _Float16* gB = Bpack + (size_t)bx * 8 * 8192;

  floatx16 acc[2][4] = {};

  STAGE(0, 0);
  asm volatile("s_waitcnt vmcnt(0)" ::: "memory");
  SCB; __builtin_amdgcn_s_barrier(); SCB;

#pragma unroll
  for (int kc = 0; kc < 8; ++kc) {
    const int bo = (kc & 1) * 8192;
    const int nbo = bo ^ 8192;

    // ks0 fragment reads (buf[kc&1] valid per barrier)
    half8 a0h[2], a0l[2], b0[4], a1h[2], a1l[2], b1[4];
#pragma unroll
    for (int i = 0; i < 2; ++i) {
      const int it = wm * 2 + i;
      a0h[i] = *reinterpret_cast<const half8*>(ldsA + bo + ((it) * 2 + lh) * 256 + l31 * 8);
      a0l[i] = *reinterpret_cast<const half8*>(ldsA + bo + ((4 + it) * 2 + lh) * 256 + l31 * 8);
    }
#pragma unroll
    for (int j = 0; j < 4; ++j) {
      const int jt = wn * 4 + j;
      b0[j] = *reinterpret_cast<const half8*>(ldsB + bo + ((jt) * 2 + lh) * 256 + l31 * 8);
    }
    // stage next kc into the other buffer (no hazard with current reads)
    if (kc < 7) { STAGE(nbo, kc + 1); }
    // ks1 fragment reads
#pragma unroll
    for (int i = 0; i < 2; ++i) {
      const int it = wm * 2 + i;
      a1h[i] = *reinterpret_cast<const half8*>(ldsA + bo + ((8 + it) * 2 + lh) * 256 + l31 * 8);
      a1l[i] = *reinterpret_cast<const half8*>(ldsA + bo + ((12 + it) * 2 + lh) * 256 + l31 * 8);
    }
#pragma unroll
    for (int j = 0; j < 4; ++j) {
      const int jt = wn * 4 + j;
      b1[j] = *reinterpret_cast<const half8*>(ldsB + bo + ((8 + jt) * 2 + lh) * 256 + l31 * 8);
    }
    // MFMA ks0 (compiler's counted lgkm lets ks1 latency hide under this)
    __builtin_amdgcn_s_setprio(1);
#pragma unroll
    for (int i = 0; i < 2; ++i)
#pragma unroll
      for (int j = 0; j < 4; ++j) {
        acc[i][j] = MFMA16(a0h[i], b0[j], acc[i][j]);
        acc[i][j] = MFMA16(a0l[i], b0[j], acc[i][j]);
      }
#pragma unroll
    for (int i = 0; i < 2; ++i)
#pragma unroll
      for (int j = 0; j < 4; ++j) {
        acc[i][j] = MFMA16(a1h[i], b1[j], acc[i][j]);
        acc[i][j] = MFMA16(a1l[i], b1[j], acc[i][j]);
      }
    __builtin_amdgcn_s_setprio(0);
    // stage(kc+1) was issued ~400cyc ago; drain then sync
    asm volatile("s_waitcnt vmcnt(0)" ::: "memory");
    SCB; __builtin_amdgcn_s_barrier(); SCB;
  }

  // epilogue: scores + per-lane top-2 over this block's 128 codes
  float b1v[4] = {-3.0e38f, -3.0e38f, -3.0e38f, -3.0e38f};
  float b2v[4] = {-3.0e38f, -3.0e38f, -3.0e38f, -3.0e38f};
  int idx1[4] = {0, 0, 0, 0};
#pragma unroll
  for (int i = 0; i < 2; ++i) {
    const int code0 = ct * 128 + wm * 64 + i * 32;
    const float* ep = en2 + code0 + 4 * lh;
    const float4 e0 = *reinterpret_cast<const float4*>(ep);
    const float4 e1 = *reinterpret_cast<const float4*>(ep + 8);
    const float4 e2 = *reinterpret_cast<const float4*>(ep + 16);
    const float4 e3 = *reinterpret_cast<const float4*>(ep + 24);
    const float ev[16] = {e0.x, e0.y, e0.z, e0.w, e1.x, e1.y, e1.z, e1.w,
                          e2.x, e2.y, e2.z, e2.w, e3.x, e3.y, e3.z, e3.w};
#pragma unroll
    for (int reg = 0; reg < 16; ++reg) {
      const int code = code0 + (reg & 3) + 8 * (reg >> 2) + 4 * lh;
#pragma unroll
      for (int j = 0; j < 4; ++j) {
        const float v = acc[i][j][reg] - ev[reg];
        if (v > b1v[j] || (v == b1v[j] && code < idx1[j])) {
          b2v[j] = b1v[j]; b1v[j] = v; idx1[j] = code;
        } else if (v > b2v[j]) {
          b2v[j] = v;
        }
      }
    }
  }

  // merge lane <-> lane^32
#pragma unroll
  for (int j = 0; j < 4; ++j) {
    const float o1 = __shfl_xor(b1v[j], 32, 64);
    const int oi = __shfl_xor(idx1[j], 32, 64);
    const float o2 = __shfl_xor(b2v[j], 32, 64);
    const bool win = (b1v[j] > o1) || (b1v[j] == o1 && idx1[j] < oi);
    const float lose1 = win ? o1 : b1v[j];
    b1v[j] = win ? b1v[j] : o1;
    idx1[j] = win ? idx1[j] : oi;
    b2v[j] = fmaxf(fmaxf(b2v[j], o2), lose1);
  }

  // cross-wave (wm) merge via LDS
  float* scr = reinterpret_cast<float*>(ldsA);
  __syncthreads();
  if (lane < 32) {
#pragma unroll
    for (int j = 0; j < 4; ++j) {
      const int rowl = wn * 128 + j * 32 + l31;
      const int base = (wm * 256 + rowl) * 3;
      scr[base + 0] = b1v[j];
      scr[base + 1] = __int_as_float(idx1[j]);
      scr[base + 2] = b2v[j];
    }
  }
  __syncthreads();
  {
    float v1 = scr[tid * 3 + 0];
    int ii = __float_as_int(scr[tid * 3 + 1]);
    float v2 = scr[tid * 3 + 2];
    const float o1 = scr[(256 + tid) * 3 + 0];
    const int oi = __float_as_int(scr[(256 + tid) * 3 + 1]);
    const float o2 = scr[(256 + tid) * 3 + 2];
    const bool win = (v1 > o1) || (v1 == o1 && ii < oi);
    const float lose1 = win ? o1 : v1;
    const float nb1 = win ? v1 : o1;
    const int ni = win ? ii : oi;
    const float nb2 = fmaxf(fmaxf(v2, o2), lose1);
    const int row = bx * 256 + tid;
    candV[(size_t)ct * M_ROWS + row] = nb1;
    candI[(size_t)ct * M_ROWS + row] = ni;
    cand2[(size_t)ct * M_ROWS + row] = nb2;
  }
}

// ---- merge splits -> index, margin; flag risky ----
__global__ void vq_reduce(const float* __restrict__ candV, const int* __restrict__ candI,
                          const float* __restrict__ cand2, int* __restrict__ ind,
                          int* __restrict__ cnt, int* __restrict__ risky,
                          unsigned long long* __restrict__ key) {
  __shared__ float sv[4][64], s2[4][64];
  __shared__ int si[4][64];
  const int tid = threadIdx.x;
  const int c = tid >> 6, r = tid & 63;
  const int row = blockIdx.x * 64 + r;
  float b1 = -3.0e38f, b2 = -3.0e38f;
  int i1 = 0;
#pragma unroll
  for (int q = 0; q < 16; ++q) {
    const int sp = c * 16 + q;
    const float v = candV[(size_t)sp * M_ROWS + row];
    const int ii = candI[(size_t)sp * M_ROWS + row];
    const float v2 = cand2[(size_t)sp * M_ROWS + row];
    if (v > b1 || (v == b1 && ii < i1)) {
      b2 = fmaxf(b1, v2); b1 = v; i1 = ii;
    } else {
      b2 = fmaxf(b2, v);
    }
  }
  sv[c][r] = b1; si[c][r] = i1; s2[c][r] = b2;
  __syncthreads();
  if (tid < 64) {
    float nb1 = sv[0][tid]; int ni = si[0][tid]; float nb2 = s2[0][tid];
#pragma unroll
    for (int cc = 1; cc < 4; ++cc) {
      const float v = sv[cc][tid];
      const int ii = si[cc][tid];
      const float v2 = s2[cc][tid];
      if (v > nb1 || (v == nb1 && ii < ni)) {
        nb2 = fmaxf(nb1, v2); nb1 = v; ni = ii;
      } else {
        nb2 = fmaxf(nb2, v);
      }
    }
    const int rr = blockIdx.x * 64 + tid;
    ind[rr] = ni;
    if (nb1 - nb2 < TAU) {
      const int p = atomicAdd(cnt, 1);
      if (p < CAP) { risky[p] = rr; key[rr] = 0ull; }
    }
  }
}

// ---- exact fp32 rescore: 256 blocks x 32 codes, 8 rows/iter ----
__global__ __launch_bounds__(256)
void vq_refine(const float* __restrict__ x, const float* __restrict__ cb,
               const float* __restrict__ en2, const int* __restrict__ cnt,
               const int* __restrict__ risky, unsigned long long* __restrict__ key) {
  __shared__ float cbs[32][260];
  __shared__ float xs[8][256];
  __shared__ int rowS[8];
  const int n0 = *cnt;
  const int n = n0 < CAP ? n0 : CAP;
  if (n == 0) return;
  const int tid = threadIdx.x;
  const int cBase = blockIdx.x * 32;
  const int cl = tid & 31, rs = tid >> 5;
#pragma unroll
  for (int q = 0; q < 32; ++q) cbs[q][tid] = cb[(size_t)(cBase + q) * K_DIM + tid];
  const float e_c = en2[cBase + cl];
  for (int t0 = 0; t0 < n; t0 += 8) {
    __syncthreads();
    if (tid < 8) {
      int ti = t0 + tid;
      rowS[tid] = risky[ti < n ? ti : n - 1];
    }
    __syncthreads();
#pragma unroll
    for (int r = 0; r < 8; ++r) xs[r][tid] = x[(size_t)rowS[r] * K_DIM + tid];
    __syncthreads();
    float s = 0.f;
#pragma unroll 8
    for (int k4 = 0; k4 < 64; ++k4) {
      const float4 xv = *reinterpret_cast<const float4*>(&xs[rs][k4 * 4]);
      const float4 cv = *reinterpret_cast<const float4*>(&cbs[cl][k4 * 4]);
      s = fmaf(xv.x, cv.x, s); s = fmaf(xv.y, cv.y, s);
      s = fmaf(xv.z, cv.z, s); s = fmaf(xv.w, cv.w, s);
    }
    const float sc = s - e_c;
    unsigned u = __float_as_uint(sc);
    u ^= (u >> 31) ? 0xFFFFFFFFu : 0x80000000u;
    unsigned long long k64 =
        ((unsigned long long)u << 32) | (unsigned)(N_CODES - 1 - (cBase + cl));
#pragma unroll
    for (int m = 16; m > 0; m >>= 1) {
      const unsigned long long o = __shfl_xor(k64, m, 64);
      if (o > k64) k64 = o;
    }
    if (cl == 0) atomicMax(key + rowS[rs], k64);
  }
}

__global__ void vq_fix(const int* __restrict__ cnt, const int* __restrict__ risky,
                       const unsigned long long* __restrict__ key, int* __restrict__ ind) {
  const int i = blockIdx.x * blockDim.x + threadIdx.x;
  const int n = *cnt < CAP ? *cnt : CAP;
  if (i < n) {
    const int r = risky[i];
    ind[r] = N_CODES - 1 - (int)(unsigned)(key[r] & 0xFFFFFFFFull);
  }
}

// ---- gather z_q, write z_q_st + indices, partial loss sums ----
__global__ void vq_gather(const float* __restrict__ x, const float* __restrict__ cb,
                          const int* __restrict__ ind, float* __restrict__ zq,
                          float* __restrict__ idxf, float* __restrict__ partial) {
  __shared__ float red[256];
  const int g = blockIdx.x * 256 + threadIdx.x;
  const int row = g >> 6;
  const int c4 = g & 63;
  const int idx = ind[row];
  if (c4 == 0) idxf[row] = (float)idx;
  const float4 z = *reinterpret_cast<const float4*>(cb + (size_t)idx * K_DIM + c4 * 4);
  const float4 xv = *reinterpret_cast<const float4*>(x + (size_t)g * 4);
  *reinterpret_cast<float4*>(zq + (size_t)g * 4) = z;
  const float dx = z.x - xv.x, dy = z.y - xv.y, dz = z.z - xv.z, dw = z.w - xv.w;
  red[threadIdx.x] = dx * dx + dy * dy + dz * dz + dw * dw;
  __syncthreads();
  for (int o = 128; o > 0; o >>= 1) {
    if (threadIdx.x < o) red[threadIdx.x] += red[threadIdx.x + o];
    __syncthreads();
  }
  if (threadIdx.x == 0) partial[blockIdx.x] = red[0];
}

__global__ void vq_loss(const float* __restrict__ partial, float* __restrict__ out) {
  __shared__ float red[256];
  float s = 0.f;
  for (int i = threadIdx.x; i < 4096; i += 256) s += partial[i];
  red[threadIdx.x] = s;
  __syncthreads();
  for (int o = 128; o > 0; o >>= 1) {
    if (threadIdx.x < o) red[threadIdx.x] += red[threadIdx.x + o];
    __syncthreads();
  }
  if (threadIdx.x == 0) out[0] = 1.25f * red[0] / 4194304.0f;
}

extern "C" void kernel_launch(void* const* d_in, const int* in_sizes, int n_in,
                              void* d_out, int out_size, void* d_ws, size_t ws_size,
                              hipStream_t stream) {
  const float* x = (const float*)d_in[0];
  const float* cb = (const float*)d_in[1];
  float* out = (float*)d_out;
  float* zq = out;
  float* loss = out + 4194304;
  float* idxf = out + 4194305;

  char* w = (char*)d_ws;
  _Float16* Apack = (_Float16*)w;                      w += (size_t)N_CODES * K_DIM * 2 * 2;
  _Float16* Bpack = (_Float16*)w;                      w += (size_t)M_ROWS * K_DIM * 2;
  unsigned long long* key = (unsigned long long*)w;    w += (size_t)M_ROWS * 8;
  float* en2 = (float*)w;                              w += (size_t)N_CODES * 4;
  float* candV = (float*)w;                            w += (size_t)M_ROWS * NSPLIT * 4;
  float* cand2 = (float*)w;                            w += (size_t)M_ROWS * NSPLIT * 4;
  int* candI = (int*)w;                                w += (size_t)M_ROWS * NSPLIT * 4;
  int* ind = (int*)w;                                  w += (size_t)M_ROWS * 4;
  int* risky = (int*)w;                                w += (size_t)CAP * 4;
  int* cnt = (int*)w;                                  w += 64;
  float* part = (float*)w;                             w += 4096 * 4;

  pack_all<<<3072, 256, 0, stream>>>(x, cb, Apack, Bpack, en2, cnt);
  vq_dist<<<4096, 256, 0, stream>>>(Apack, Bpack, en2, candV, candI, cand2);
  vq_reduce<<<256, 256, 0, stream>>>(candV, candI, cand2, ind, cnt, risky, key);
  vq_refine<<<256, 256, 0, stream>>>(x, cb, en2, cnt, risky, key);
  vq_fix<<<CAP / 256, 256, 0, stream>>>(cnt, risky, key, ind);
  vq_gather<<<4194304 / (256 * 4), 256, 0, stream>>>(x, cb, ind, zq, idxf, part);
  vq_loss<<<1, 256, 0, stream>>>(part, loss);
}

// Round 9
// 247.495 us; speedup vs baseline: 1.5001x; 1.0707x over previous
//
#include <hip/hip_runtime.h>

#define M_ROWS 16384
#define N_CODES 8192
#define K_DIM   256
#define NSPLIT  16
#define CAP     16384
#define TAU     0.05f

typedef _Float16 half8 __attribute__((ext_vector_type(8)));
typedef float floatx16 __attribute__((ext_vector_type(16)));

#define GLL16(g, l) __builtin_amdgcn_global_load_lds(                         \
    (const __attribute__((address_space(1))) void*)(g),                       \
    (__attribute__((address_space(3))) void*)(l), 16, 0, 0)

#define MFMA16(a, b, c) __builtin_amdgcn_mfma_f32_32x32x16_f16(a, b, c, 0, 0, 0)
#define SCB __builtin_amdgcn_sched_barrier(0)

// ---- fused pack: codebook(h+l, 32-code tiles)+en2, x(h, 128-row tiles), cnt ----
// A blob per (ct32, kc32): [pl2][ks2][lh2][rr32][j8] = 2048 fp16 (4KB)
// B blob per (rt128, kc32): [jt4][ks2][lh2][rr32][j8] = 4096 fp16 (8KB)
__global__ void pack_all(const float* __restrict__ x, const float* __restrict__ cb,
                         _Float16* __restrict__ Apack, _Float16* __restrict__ Bpack,
                         float* __restrict__ en2, int* __restrict__ cnt) {
  const int bid = blockIdx.x;
  const int tid = threadIdx.x;
  if (bid == 0 && tid == 0) *cnt = 0;
  if (bid < 1024) {
    const int t = bid * 256 + tid;
    const int C = t >> 5, G = t & 31;
    const int ct = C >> 5, r32 = C & 31;
    const int kc = G >> 2, g2 = G & 3, ks = g2 >> 1, lh = g2 & 1;
    const float* src = cb + (size_t)C * K_DIM + G * 8;
    half8 hv, lv;
    float ss = 0.f;
#pragma unroll
    for (int j = 0; j < 8; ++j) {
      const float v = src[j];
      const _Float16 h = (_Float16)v;
      hv[j] = h;
      lv[j] = (_Float16)(v - (float)h);
      ss += v * v;
    }
    ss += __shfl_xor(ss, 1, 32); ss += __shfl_xor(ss, 2, 32);
    ss += __shfl_xor(ss, 4, 32); ss += __shfl_xor(ss, 8, 32);
    ss += __shfl_xor(ss, 16, 32);
    if (G == 0) en2[C] = 0.5f * ss;
    _Float16* blob = Apack + ((size_t)ct * 8 + kc) * 2048;
    const int offh = ((0 * 2 + ks) * 2 + lh) * 256 + r32 * 8;
    const int offl = ((1 * 2 + ks) * 2 + lh) * 256 + r32 * 8;
    *reinterpret_cast<half8*>(blob + offh) = hv;
    *reinterpret_cast<half8*>(blob + offl) = lv;
  } else {
    const int t = (bid - 1024) * 256 + tid;
    const int R = t >> 5, G = t & 31;
    const int rt = R >> 7, r = R & 127, jt = r >> 5, rr = r & 31;
    const int kc = G >> 2, g2 = G & 3, ks = g2 >> 1, lh = g2 & 1;
    const float* src = x + (size_t)R * K_DIM + G * 8;
    half8 hv;
#pragma unroll
    for (int j = 0; j < 8; ++j) hv[j] = (_Float16)src[j];
    _Float16* blob = Bpack + ((size_t)rt * 8 + kc) * 4096;
    const int off = ((jt * 2 + ks) * 2 + lh) * 256 + rr * 8;
    *reinterpret_cast<half8*>(blob + off) = hv;
  }
}

// ---- barrier-free distance kernel ----
// block: 128 x-rows (B full-K in LDS, staged once) x 128 codes-per-chunk-group;
// 4 waves, each 32 codes x 128 rows; A streamed global->reg, 1-kc prefetch.
// grid 512 = 128 bx x 4 cs (single round, 2 blocks/CU). ZERO barriers in K-loop.
__global__ __launch_bounds__(256, 2)
void vq_dist(const _Float16* __restrict__ Apack, const _Float16* __restrict__ Bpack,
             const float* __restrict__ en2, float* __restrict__ candV,
             int* __restrict__ candI, float* __restrict__ cand2) {
  __shared__ _Float16 ldsB[32768];   // 64KB: 128 rows x 256 K (h), blob order

  const int tid = threadIdx.x;
  const int wv = tid >> 6, lane = tid & 63;
  const int l31 = lane & 31, lh = lane >> 5;

  // XCD mapping: cs (A-quarter) pinned per XCD-pair -> A stays L2-resident
  const int lid = blockIdx.x;          // 0..511
  const int xcd = lid & 7, q = lid >> 3;
  const int cs = xcd >> 1;             // 0..3
  const int bx = q * 2 + (xcd & 1);    // 0..127

  // stage B once: 64KB, 16 GLL per thread, lane-linear
  const _Float16* gB = Bpack + (size_t)bx * 32768;
#pragma unroll
  for (int s = 0; s < 16; ++s)
    GLL16(gB + (s * 256 + tid) * 8, ldsB + (s * 256 + tid) * 8);

  // prologue A loads: chunk 0, kc 0  (tile = cs*64 + c*4 + wv)
  const int tile0 = cs * 64 + wv;
  half8 a[2][4];   // [parity][pl*2+ks]
  {
    const _Float16* gA = Apack + ((size_t)tile0 * 8) * 2048;
#pragma unroll
    for (int u = 0; u < 4; ++u)
      a[0][u] = *reinterpret_cast<const half8*>(gA + (u * 2 + lh) * 256 + l31 * 8);
  }

  asm volatile("s_waitcnt vmcnt(4)" ::: "memory");   // B staged (A batch may fly)
  SCB;
  __builtin_amdgcn_s_barrier();                      // the ONLY block barrier
  SCB;

  float b1[4] = {-3.0e38f, -3.0e38f, -3.0e38f, -3.0e38f};
  float b2[4] = {-3.0e38f, -3.0e38f, -3.0e38f, -3.0e38f};
  int i1[4] = {0, 0, 0, 0};

  for (int c = 0; c < 16; ++c) {
    const int tile = cs * 64 + c * 4 + wv;
    floatx16 acc[4] = {};
#pragma unroll
    for (int kc = 0; kc < 8; ++kc) {
      const int par = kc & 1, npar = par ^ 1;
      // prefetch next A batch (next kc, or next chunk's kc0)
      if (!(c == 15 && kc == 7)) {
        const int ntile = (kc < 7) ? tile : (tile + 4);
        const int nkc = (kc < 7) ? (kc + 1) : 0;
        const _Float16* gA = Apack + ((size_t)ntile * 8 + nkc) * 2048;
#pragma unroll
        for (int u = 0; u < 4; ++u)
          a[npar][u] = *reinterpret_cast<const half8*>(gA + (u * 2 + lh) * 256 + l31 * 8);
      }
      SCB;   // keep prefetch issued before compute
      // B fragments from LDS
      half8 b[4][2];   // [jt][ks]
#pragma unroll
      for (int jt = 0; jt < 4; ++jt)
#pragma unroll
        for (int ks = 0; ks < 2; ++ks)
          b[jt][ks] = *reinterpret_cast<const half8*>(
              ldsB + kc * 4096 + ((jt * 2 + ks) * 2 + lh) * 256 + l31 * 8);
      // 16 MFMA (compiler inserts exact vmcnt/lgkm waits)
      __builtin_amdgcn_s_setprio(1);
#pragma unroll
      for (int ks = 0; ks < 2; ++ks)
#pragma unroll
        for (int pl = 0; pl < 2; ++pl)
#pragma unroll
          for (int jt = 0; jt < 4; ++jt)
            acc[jt] = MFMA16(a[par][pl * 2 + ks], b[jt][ks], acc[jt]);
      __builtin_amdgcn_s_setprio(0);
    }

    // chunk epilogue: scores + running top-2 (per lane, per jt-row)
    const int code0 = tile * 32;
    const float* ep = en2 + code0 + 4 * lh;
    const float4 e0 = *reinterpret_cast<const float4*>(ep);
    const float4 e1 = *reinterpret_cast<const float4*>(ep + 8);
    const float4 e2 = *reinterpret_cast<const float4*>(ep + 16);
    const float4 e3 = *reinterpret_cast<const float4*>(ep + 24);
    const float ev[16] = {e0.x, e0.y, e0.z, e0.w, e1.x, e1.y, e1.z, e1.w,
                          e2.x, e2.y, e2.z, e2.w, e3.x, e3.y, e3.z, e3.w};
#pragma unroll
    for (int reg = 0; reg < 16; ++reg) {
      const int code = code0 + (reg & 3) + 8 * (reg >> 2) + 4 * lh;
#pragma unroll
      for (int jt = 0; jt < 4; ++jt) {
        const float v = acc[jt][reg] - ev[reg];
        if (v > b1[jt] || (v == b1[jt] && code < i1[jt])) {
          b2[jt] = b1[jt]; b1[jt] = v; i1[jt] = code;
        } else if (v > b2[jt]) {
          b2[jt] = v;
        }
      }
    }
  }

  // merge lane <-> lane^32 (same x-row, disjoint code subsets)
#pragma unroll
  for (int jt = 0; jt < 4; ++jt) {
    const float o1 = __shfl_xor(b1[jt], 32, 64);
    const int oi = __shfl_xor(i1[jt], 32, 64);
    const float o2 = __shfl_xor(b2[jt], 32, 64);
    const bool win = (b1[jt] > o1) || (b1[jt] == o1 && i1[jt] < oi);
    const float lose1 = win ? o1 : b1[jt];
    b1[jt] = win ? b1[jt] : o1;
    i1[jt] = win ? i1[jt] : oi;
    b2[jt] = fmaxf(fmaxf(b2[jt], o2), lose1);
  }

  // write per-wave split (no cross-wave merge, no barrier)
  if (lane < 32) {
    const int split = cs * 4 + wv;
#pragma unroll
    for (int jt = 0; jt < 4; ++jt) {
      const int row = bx * 128 + jt * 32 + l31;
      candV[(size_t)split * M_ROWS + row] = b1[jt];
      candI[(size_t)split * M_ROWS + row] = i1[jt];
      cand2[(size_t)split * M_ROWS + row] = b2[jt];
    }
  }
}

// ---- merge 16 splits -> index, margin; flag risky (coalesced) ----
__global__ void vq_reduce(const float* __restrict__ candV, const int* __restrict__ candI,
                          const float* __restrict__ cand2, int* __restrict__ ind,
                          int* __restrict__ cnt, int* __restrict__ risky,
                          unsigned long long* __restrict__ key) {
  const int row = blockIdx.x * 256 + threadIdx.x;
  float b1 = candV[row];
  int i1 = candI[row];
  float b2 = cand2[row];
#pragma unroll
  for (int s = 1; s < NSPLIT; ++s) {
    const float v = candV[(size_t)s * M_ROWS + row];
    const int ii = candI[(size_t)s * M_ROWS + row];
    const float v2 = cand2[(size_t)s * M_ROWS + row];
    if (v > b1 || (v == b1 && ii < i1)) {
      b2 = fmaxf(b1, v2); b1 = v; i1 = ii;
    } else {
      b2 = fmaxf(b2, v);
    }
  }
  ind[row] = i1;
  if (b1 - b2 < TAU) {
    const int p = atomicAdd(cnt, 1);
    if (p < CAP) { risky[p] = row; key[row] = 0ull; }
  }
}

// ---- exact fp32 rescore: 256 blocks x 32 codes, 8 rows/iter ----
__global__ __launch_bounds__(256)
void vq_refine(const float* __restrict__ x, const float* __restrict__ cb,
               const float* __restrict__ en2, const int* __restrict__ cnt,
               const int* __restrict__ risky, unsigned long long* __restrict__ key) {
  __shared__ float cbs[32][260];
  __shared__ float xs[8][256];
  __shared__ int rowS[8];
  const int n0 = *cnt;
  const int n = n0 < CAP ? n0 : CAP;
  if (n == 0) return;
  const int tid = threadIdx.x;
  const int cBase = blockIdx.x * 32;
  const int cl = tid & 31, rs = tid >> 5;
#pragma unroll
  for (int q = 0; q < 32; ++q) cbs[q][tid] = cb[(size_t)(cBase + q) * K_DIM + tid];
  const float e_c = en2[cBase + cl];
  for (int t0 = 0; t0 < n; t0 += 8) {
    __syncthreads();
    if (tid < 8) {
      int ti = t0 + tid;
      rowS[tid] = risky[ti < n ? ti : n - 1];
    }
    __syncthreads();
#pragma unroll
    for (int r = 0; r < 8; ++r) xs[r][tid] = x[(size_t)rowS[r] * K_DIM + tid];
    __syncthreads();
    float s = 0.f;
#pragma unroll 8
    for (int k4 = 0; k4 < 64; ++k4) {
      const float4 xv = *reinterpret_cast<const float4*>(&xs[rs][k4 * 4]);
      const float4 cv = *reinterpret_cast<const float4*>(&cbs[cl][k4 * 4]);
      s = fmaf(xv.x, cv.x, s); s = fmaf(xv.y, cv.y, s);
      s = fmaf(xv.z, cv.z, s); s = fmaf(xv.w, cv.w, s);
    }
    const float sc = s - e_c;
    unsigned u = __float_as_uint(sc);
    u ^= (u >> 31) ? 0xFFFFFFFFu : 0x80000000u;
    unsigned long long k64 =
        ((unsigned long long)u << 32) | (unsigned)(N_CODES - 1 - (cBase + cl));
#pragma unroll
    for (int m = 16; m > 0; m >>= 1) {
      const unsigned long long o = __shfl_xor(k64, m, 64);
      if (o > k64) k64 = o;
    }
    if (cl == 0) atomicMax(key + rowS[rs], k64);
  }
}

__global__ void vq_fix(const int* __restrict__ cnt, const int* __restrict__ risky,
                       const unsigned long long* __restrict__ key, int* __restrict__ ind) {
  const int i = blockIdx.x * blockDim.x + threadIdx.x;
  const int n = *cnt < CAP ? *cnt : CAP;
  if (i < n) {
    const int r = risky[i];
    ind[r] = N_CODES - 1 - (int)(unsigned)(key[r] & 0xFFFFFFFFull);
  }
}

// ---- gather z_q, write z_q_st + indices, partial loss sums ----
__global__ void vq_gather(const float* __restrict__ x, const float* __restrict__ cb,
                          const int* __restrict__ ind, float* __restrict__ zq,
                          float* __restrict__ idxf, float* __restrict__ partial) {
  __shared__ float red[256];
  const int g = blockIdx.x * 256 + threadIdx.x;
  const int row = g >> 6;
  const int c4 = g & 63;
  const int idx = ind[row];
  if (c4 == 0) idxf[row] = (float)idx;
  const float4 z = *reinterpret_cast<const float4*>(cb + (size_t)idx * K_DIM + c4 * 4);
  const float4 xv = *reinterpret_cast<const float4*>(x + (size_t)g * 4);
  *reinterpret_cast<float4*>(zq + (size_t)g * 4) = z;
  const float dx = z.x - xv.x, dy = z.y - xv.y, dz = z.z - xv.z, dw = z.w - xv.w;
  red[threadIdx.x] = dx * dx + dy * dy + dz * dz + dw * dw;
  __syncthreads();
  for (int o = 128; o > 0; o >>= 1) {
    if (threadIdx.x < o) red[threadIdx.x] += red[threadIdx.x + o];
    __syncthreads();
  }
  if (threadIdx.x == 0) partial[blockIdx.x] = red[0];
}

__global__ void vq_loss(const float* __restrict__ partial, float* __restrict__ out) {
  __shared__ float red[256];
  float s = 0.f;
  for (int i = threadIdx.x; i < 4096; i += 256) s += partial[i];
  red[threadIdx.x] = s;
  __syncthreads();
  for (int o = 128; o > 0; o >>= 1) {
    if (threadIdx.x < o) red[threadIdx.x] += red[threadIdx.x + o];
    __syncthreads();
  }
  if (threadIdx.x == 0) out[0] = 1.25f * red[0] / 4194304.0f;
}

extern "C" void kernel_launch(void* const* d_in, const int* in_sizes, int n_in,
                              void* d_out, int out_size, void* d_ws, size_t ws_size,
                              hipStream_t stream) {
  const float* x = (const float*)d_in[0];
  const float* cb = (const float*)d_in[1];
  float* out = (float*)d_out;
  float* zq = out;
  float* loss = out + 4194304;
  float* idxf = out + 4194305;

  char* w = (char*)d_ws;
  _Float16* Apack = (_Float16*)w;                      w += (size_t)N_CODES * K_DIM * 2 * 2;   // 8MB h+l
  _Float16* Bpack = (_Float16*)w;                      w += (size_t)M_ROWS * K_DIM * 2;        // 8MB h
  unsigned long long* key = (unsigned long long*)w;    w += (size_t)M_ROWS * 8;
  float* en2 = (float*)w;                              w += (size_t)N_CODES * 4;
  float* candV = (float*)w;                            w += (size_t)M_ROWS * NSPLIT * 4;
  float* cand2 = (float*)w;                            w += (size_t)M_ROWS * NSPLIT * 4;
  int* candI = (int*)w;                                w += (size_t)M_ROWS * NSPLIT * 4;
  int* ind = (int*)w;                                  w += (size_t)M_ROWS * 4;
  int* risky = (int*)w;                                w += (size_t)CAP * 4;
  int* cnt = (int*)w;                                  w += 64;
  float* part = (float*)w;                             w += 4096 * 4;

  pack_all<<<3072, 256, 0, stream>>>(x, cb, Apack, Bpack, en2, cnt);
  vq_dist<<<512, 256, 0, stream>>>(Apack, Bpack, en2, candV, candI, cand2);
  vq_reduce<<<M_ROWS / 256, 256, 0, stream>>>(candV, candI, cand2, ind, cnt, risky, key);
  vq_refine<<<256, 256, 0, stream>>>(x, cb, en2, cnt, risky, key);
  vq_fix<<<CAP / 256, 256, 0, stream>>>(cnt, risky, key, ind);
  vq_gather<<<4194304 / (256 * 4), 256, 0, stream>>>(x, cb, ind, zq, idxf, part);
  vq_loss<<<1, 256, 0, stream>>>(part, loss);
}

// Round 10
// 246.415 us; speedup vs baseline: 1.5066x; 1.0044x over previous
//
#include <hip/hip_runtime.h>

#define M_ROWS 16384
#define N_CODES 8192
#define K_DIM   256
#define NSPLIT  16
#define CAP     16384
#define TAU     0.12f

typedef _Float16 half8 __attribute__((ext_vector_type(8)));
typedef float floatx16 __attribute__((ext_vector_type(16)));

#define GLL16(g, l) __builtin_amdgcn_global_load_lds(                         \
    (const __attribute__((address_space(1))) void*)(g),                       \
    (__attribute__((address_space(3))) void*)(l), 16, 0, 0)

#define MFMA16(a, b, c) __builtin_amdgcn_mfma_f32_32x32x16_f16(a, b, c, 0, 0, 0)
#define SCB __builtin_amdgcn_sched_barrier(0)

// ---- fused pack: codebook h-only + en2 + cnt zero; x h-only ----
// A blob per (ct32, kc32): [ks2][lh2][rr32][j8] = 1024 fp16 (2KB)
// B blob per (rt128, kc32): [jt4][ks2][lh2][rr32][j8] = 4096 fp16 (8KB)
__global__ void pack_all(const float* __restrict__ x, const float* __restrict__ cb,
                         _Float16* __restrict__ Apack, _Float16* __restrict__ Bpack,
                         float* __restrict__ en2, int* __restrict__ cnt) {
  const int bid = blockIdx.x;
  const int tid = threadIdx.x;
  if (bid == 0 && tid == 0) *cnt = 0;
  if (bid < 1024) {
    const int t = bid * 256 + tid;
    const int C = t >> 5, G = t & 31;
    const int ct = C >> 5, r32 = C & 31;
    const int kc = G >> 2, g2 = G & 3, ks = g2 >> 1, lh = g2 & 1;
    const float* src = cb + (size_t)C * K_DIM + G * 8;
    half8 hv;
    float ss = 0.f;
#pragma unroll
    for (int j = 0; j < 8; ++j) {
      const float v = src[j];
      hv[j] = (_Float16)v;
      ss += v * v;
    }
    ss += __shfl_xor(ss, 1, 32); ss += __shfl_xor(ss, 2, 32);
    ss += __shfl_xor(ss, 4, 32); ss += __shfl_xor(ss, 8, 32);
    ss += __shfl_xor(ss, 16, 32);
    if (G == 0) en2[C] = 0.5f * ss;
    _Float16* blob = Apack + ((size_t)ct * 8 + kc) * 1024;
    const int off = ((ks * 2 + lh) * 32 + r32) * 8;
    *reinterpret_cast<half8*>(blob + off) = hv;
  } else {
    const int t = (bid - 1024) * 256 + tid;
    const int R = t >> 5, G = t & 31;
    const int rt = R >> 7, r = R & 127, jt = r >> 5, rr = r & 31;
    const int kc = G >> 2, g2 = G & 3, ks = g2 >> 1, lh = g2 & 1;
    const float* src = x + (size_t)R * K_DIM + G * 8;
    half8 hv;
#pragma unroll
    for (int j = 0; j < 8; ++j) hv[j] = (_Float16)src[j];
    _Float16* blob = Bpack + ((size_t)rt * 8 + kc) * 4096;
    const int off = ((jt * 2 + ks) * 2 + lh) * 256 + rr * 8;
    *reinterpret_cast<half8*>(blob + off) = hv;
  }
}

// ---- barrier-free h-only distance kernel ----
// block: 128 x-rows (B full-K in LDS once) x 2048 codes (4 waves x 512);
// wave tile 64 codes x 128 rows; A streamed global->reg, 1-kc prefetch.
// grid 512 (2 blocks/CU), ZERO K-loop barriers.
__global__ __launch_bounds__(256, 2)
void vq_dist(const _Float16* __restrict__ Apack, const _Float16* __restrict__ Bpack,
             const float* __restrict__ en2, float* __restrict__ candV,
             int* __restrict__ candI, float* __restrict__ cand2) {
  __shared__ _Float16 ldsB[32768];   // 64KB

  const int tid = threadIdx.x;
  const int wv = tid >> 6, lane = tid & 63;
  const int l31 = lane & 31, lh = lane >> 5;

  const int lid = blockIdx.x;          // 0..511
  const int xcd = lid & 7, q = lid >> 3;
  const int cs = xcd >> 1;             // 0..3 (A-quarter pinned per XCD pair)
  const int bx = q * 2 + (xcd & 1);    // 0..127

  const _Float16* gB = Bpack + (size_t)bx * 32768;
#pragma unroll
  for (int s = 0; s < 16; ++s)
    GLL16(gB + (s * 256 + tid) * 8, ldsB + (s * 256 + tid) * 8);

  // tiles for this wave: t0(c) = (cs*4+wv)*16 + c*2, it in {0,1}
  const int tbase = (cs * 4 + wv) * 16;
  half8 a[2][2][2];   // [parity][it][ks]
  {
    const _Float16* gA0 = Apack + ((size_t)tbase) * 8192;       // tile stride 8*1024
#pragma unroll
    for (int it = 0; it < 2; ++it)
#pragma unroll
      for (int ks = 0; ks < 2; ++ks)
        a[0][it][ks] = *reinterpret_cast<const half8*>(
            gA0 + (size_t)it * 8192 + ((ks * 2 + lh) * 32 + l31) * 8);
  }

  asm volatile("s_waitcnt vmcnt(4)" ::: "memory");
  SCB;
  __builtin_amdgcn_s_barrier();        // only block barrier
  SCB;

  float b1[4] = {-3.0e38f, -3.0e38f, -3.0e38f, -3.0e38f};
  float b2[4] = {-3.0e38f, -3.0e38f, -3.0e38f, -3.0e38f};
  int i1[4] = {0, 0, 0, 0};

  for (int c = 0; c < 8; ++c) {
    const int t0 = tbase + c * 2;
    floatx16 acc[2][4] = {};
#pragma unroll
    for (int kc = 0; kc < 8; ++kc) {
      const int par = kc & 1, npar = par ^ 1;
      if (!(c == 7 && kc == 7)) {
        const int nt0 = (kc < 7) ? t0 : (t0 + 2);
        const int nkc = (kc < 7) ? (kc + 1) : 0;
        const _Float16* gA = Apack + ((size_t)nt0 * 8 + nkc) * 1024;
#pragma unroll
        for (int it = 0; it < 2; ++it)
#pragma unroll
          for (int ks = 0; ks < 2; ++ks)
            a[npar][it][ks] = *reinterpret_cast<const half8*>(
                gA + (size_t)it * 8192 + ((ks * 2 + lh) * 32 + l31) * 8);
      }
      SCB;
      half8 b[4][2];
#pragma unroll
      for (int jt = 0; jt < 4; ++jt)
#pragma unroll
        for (int ks = 0; ks < 2; ++ks)
          b[jt][ks] = *reinterpret_cast<const half8*>(
              ldsB + kc * 4096 + ((jt * 2 + ks) * 2 + lh) * 256 + l31 * 8);
      __builtin_amdgcn_s_setprio(1);
#pragma unroll
      for (int ks = 0; ks < 2; ++ks)
#pragma unroll
        for (int it = 0; it < 2; ++it)
#pragma unroll
          for (int jt = 0; jt < 4; ++jt)
            acc[it][jt] = MFMA16(a[par][it][ks], b[jt][ks], acc[it][jt]);
      __builtin_amdgcn_s_setprio(0);
    }

    // epilogue: scores + top-2 (no tie-break: ties -> margin 0 -> refined)
#pragma unroll
    for (int it = 0; it < 2; ++it) {
      const int code0 = (t0 + it) * 32;
      const float* ep = en2 + code0 + 4 * lh;
      const float4 e0 = *reinterpret_cast<const float4*>(ep);
      const float4 e1 = *reinterpret_cast<const float4*>(ep + 8);
      const float4 e2 = *reinterpret_cast<const float4*>(ep + 16);
      const float4 e3 = *reinterpret_cast<const float4*>(ep + 24);
      const float ev[16] = {e0.x, e0.y, e0.z, e0.w, e1.x, e1.y, e1.z, e1.w,
                            e2.x, e2.y, e2.z, e2.w, e3.x, e3.y, e3.z, e3.w};
#pragma unroll
      for (int reg = 0; reg < 16; ++reg) {
        const int code = code0 + (reg & 3) + 8 * (reg >> 2) + 4 * lh;
#pragma unroll
        for (int jt = 0; jt < 4; ++jt) {
          const float v = acc[it][jt][reg] - ev[reg];
          b2[jt] = fmaxf(b2[jt], fminf(v, b1[jt]));
          i1[jt] = (v > b1[jt]) ? code : i1[jt];
          b1[jt] = fmaxf(b1[jt], v);
        }
      }
    }
  }

  // merge lane <-> lane^32 (same rows, disjoint codes)
#pragma unroll
  for (int jt = 0; jt < 4; ++jt) {
    const float o1 = __shfl_xor(b1[jt], 32, 64);
    const int oi = __shfl_xor(i1[jt], 32, 64);
    const float o2 = __shfl_xor(b2[jt], 32, 64);
    const float lose = fminf(b1[jt], o1);
    i1[jt] = (b1[jt] >= o1) ? i1[jt] : oi;
    b1[jt] = fmaxf(b1[jt], o1);
    b2[jt] = fmaxf(fmaxf(b2[jt], o2), lose);
  }

  if (lane < 32) {
    const int split = cs * 4 + wv;
#pragma unroll
    for (int jt = 0; jt < 4; ++jt) {
      const int row = bx * 128 + jt * 32 + l31;
      candV[(size_t)split * M_ROWS + row] = b1[jt];
      candI[(size_t)split * M_ROWS + row] = i1[jt];
      cand2[(size_t)split * M_ROWS + row] = b2[jt];
    }
  }
}

// ---- merge 16 splits -> packed key; flag risky ----
__global__ void vq_reduce(const float* __restrict__ candV, const int* __restrict__ candI,
                          const float* __restrict__ cand2, int* __restrict__ cnt,
                          int* __restrict__ risky, unsigned long long* __restrict__ key) {
  const int row = blockIdx.x * 256 + threadIdx.x;
  float b1 = candV[row];
  int i1 = candI[row];
  float b2 = cand2[row];
#pragma unroll
  for (int s = 1; s < NSPLIT; ++s) {
    const float v = candV[(size_t)s * M_ROWS + row];
    const int ii = candI[(size_t)s * M_ROWS + row];
    const float v2 = cand2[(size_t)s * M_ROWS + row];
    const float lose = fminf(b1, v);
    i1 = (v > b1) ? ii : i1;
    b1 = fmaxf(b1, v);
    b2 = fmaxf(fmaxf(b2, v2), lose);
  }
  if (b1 - b2 < TAU) {
    key[row] = 0ull;
    const int p = atomicAdd(cnt, 1);
    if (p < CAP) risky[p] = row;
  } else {
    unsigned u = __float_as_uint(b1);
    u ^= (u >> 31) ? 0xFFFFFFFFu : 0x80000000u;
    key[row] = ((unsigned long long)u << 32) | (unsigned)(N_CODES - 1 - i1);
  }
}

// ---- exact fp32 rescore of risky rows: 256 blocks x 32 codes, 8 rows/iter ----
__global__ __launch_bounds__(256)
void vq_refine(const float* __restrict__ x, const float* __restrict__ cb,
               const float* __restrict__ en2, const int* __restrict__ cnt,
               const int* __restrict__ risky, unsigned long long* __restrict__ key) {
  __shared__ float cbs[32][260];
  __shared__ float xs[8][256];
  __shared__ int rowS[8];
  const int n0 = *cnt;
  const int n = n0 < CAP ? n0 : CAP;
  if (n == 0) return;
  const int tid = threadIdx.x;
  const int cBase = blockIdx.x * 32;
  const int cl = tid & 31, rs = tid >> 5;
#pragma unroll
  for (int q = 0; q < 32; ++q) cbs[q][tid] = cb[(size_t)(cBase + q) * K_DIM + tid];
  const float e_c = en2[cBase + cl];
  for (int t0 = 0; t0 < n; t0 += 8) {
    __syncthreads();
    if (tid < 8) {
      int ti = t0 + tid;
      rowS[tid] = risky[ti < n ? ti : n - 1];
    }
    __syncthreads();
#pragma unroll
    for (int r = 0; r < 8; ++r) xs[r][tid] = x[(size_t)rowS[r] * K_DIM + tid];
    __syncthreads();
    float s = 0.f;
#pragma unroll 8
    for (int k4 = 0; k4 < 64; ++k4) {
      const float4 xv = *reinterpret_cast<const float4*>(&xs[rs][k4 * 4]);
      const float4 cv = *reinterpret_cast<const float4*>(&cbs[cl][k4 * 4]);
      s = fmaf(xv.x, cv.x, s); s = fmaf(xv.y, cv.y, s);
      s = fmaf(xv.z, cv.z, s); s = fmaf(xv.w, cv.w, s);
    }
    const float sc = s - e_c;
    unsigned u = __float_as_uint(sc);
    u ^= (u >> 31) ? 0xFFFFFFFFu : 0x80000000u;
    unsigned long long k64 =
        ((unsigned long long)u << 32) | (unsigned)(N_CODES - 1 - (cBase + cl));
#pragma unroll
    for (int m = 16; m > 0; m >>= 1) {
      const unsigned long long o = __shfl_xor(k64, m, 64);
      if (o > k64) k64 = o;
    }
    if (cl == 0) atomicMax(key + rowS[rs], k64);
  }
}

// ---- gather z_q from key, write z_q_st + indices, partial loss sums ----
__global__ void vq_gather(const float* __restrict__ x, const float* __restrict__ cb,
                          const unsigned long long* __restrict__ key, float* __restrict__ zq,
                          float* __restrict__ idxf, float* __restrict__ partial) {
  __shared__ float red[256];
  const int g = blockIdx.x * 256 + threadIdx.x;
  const int row = g >> 6;
  const int c4 = g & 63;
  const int idx = N_CODES - 1 - (int)(unsigned)(key[row] & 0xFFFFFFFFull);
  if (c4 == 0) idxf[row] = (float)idx;
  const float4 z = *reinterpret_cast<const float4*>(cb + (size_t)idx * K_DIM + c4 * 4);
  const float4 xv = *reinterpret_cast<const float4*>(x + (size_t)g * 4);
  *reinterpret_cast<float4*>(zq + (size_t)g * 4) = z;
  const float dx = z.x - xv.x, dy = z.y - xv.y, dz = z.z - xv.z, dw = z.w - xv.w;
  red[threadIdx.x] = dx * dx + dy * dy + dz * dz + dw * dw;
  __syncthreads();
  for (int o = 128; o > 0; o >>= 1) {
    if (threadIdx.x < o) red[threadIdx.x] += red[threadIdx.x + o];
    __syncthreads();
  }
  if (threadIdx.x == 0) partial[blockIdx.x] = red[0];
}

__global__ void vq_loss(const float* __restrict__ partial, float* __restrict__ out) {
  __shared__ float red[256];
  float s = 0.f;
  for (int i = threadIdx.x; i < 4096; i += 256) s += partial[i];
  red[threadIdx.x] = s;
  __syncthreads();
  for (int o = 128; o > 0; o >>= 1) {
    if (threadIdx.x < o) red[threadIdx.x] += red[threadIdx.x + o];
    __syncthreads();
  }
  if (threadIdx.x == 0) out[0] = 1.25f * red[0] / 4194304.0f;
}

extern "C" void kernel_launch(void* const* d_in, const int* in_sizes, int n_in,
                              void* d_out, int out_size, void* d_ws, size_t ws_size,
                              hipStream_t stream) {
  const float* x = (const float*)d_in[0];
  const float* cb = (const float*)d_in[1];
  float* out = (float*)d_out;
  float* zq = out;
  float* loss = out + 4194304;
  float* idxf = out + 4194305;

  char* w = (char*)d_ws;
  _Float16* Apack = (_Float16*)w;                      w += (size_t)N_CODES * K_DIM * 2;   // 4MB h
  _Float16* Bpack = (_Float16*)w;                      w += (size_t)M_ROWS * K_DIM * 2;    // 8MB h
  unsigned long long* key = (unsigned long long*)w;    w += (size_t)M_ROWS * 8;
  float* en2 = (float*)w;                              w += (size_t)N_CODES * 4;
  float* candV = (float*)w;                            w += (size_t)M_ROWS * NSPLIT * 4;
  float* cand2 = (float*)w;                            w += (size_t)M_ROWS * NSPLIT * 4;
  int* candI = (int*)w;                                w += (size_t)M_ROWS * NSPLIT * 4;
  int* risky = (int*)w;                                w += (size_t)CAP * 4;
  int* cnt = (int*)w;                                  w += 64;
  float* part = (float*)w;                             w += 4096 * 4;

  pack_all<<<3072, 256, 0, stream>>>(x, cb, Apack, Bpack, en2, cnt);
  vq_dist<<<512, 256, 0, stream>>>(Apack, Bpack, en2, candV, candI, cand2);
  vq_reduce<<<M_ROWS / 256, 256, 0, stream>>>(candV, candI, cand2, cnt, risky, key);
  vq_refine<<<256, 256, 0, stream>>>(x, cb, en2, cnt, risky, key);
  vq_gather<<<4194304 / (256 * 4), 256, 0, stream>>>(x, cb, key, zq, idxf, part);
  vq_loss<<<1, 256, 0, stream>>>(part, loss);
}

// Round 11
// 221.490 us; speedup vs baseline: 1.6762x; 1.1125x over previous
//
#include <hip/hip_runtime.h>

#define M_ROWS 16384
#define N_CODES 8192
#define K_DIM   256
#define NSPLIT  16
#define CAP     16384
#define TAU     0.05f

typedef _Float16 half8 __attribute__((ext_vector_type(8)));
typedef float floatx16 __attribute__((ext_vector_type(16)));

#define GLL16(g, l) __builtin_amdgcn_global_load_lds(                         \
    (const __attribute__((address_space(1))) void*)(g),                       \
    (__attribute__((address_space(3))) void*)(l), 16, 0, 0)

#define MFMA16(a, b, c) __builtin_amdgcn_mfma_f32_32x32x16_f16(a, b, c, 0, 0, 0)
#define SCB __builtin_amdgcn_sched_barrier(0)

// ---- fused pack: codebook h-only + en2 + cnt zero; x h-only ----
// A blob per (ct32, kc32): [ks2][lh2][rr32][j8] = 1024 fp16 (2KB)
// B blob per (rt128, kc32): [jt4][ks2][lh2][rr32][j8] = 4096 fp16 (8KB)
__global__ void pack_all(const float* __restrict__ x, const float* __restrict__ cb,
                         _Float16* __restrict__ Apack, _Float16* __restrict__ Bpack,
                         float* __restrict__ en2, int* __restrict__ cnt) {
  const int bid = blockIdx.x;
  const int tid = threadIdx.x;
  if (bid == 0 && tid == 0) *cnt = 0;
  if (bid < 1024) {
    const int t = bid * 256 + tid;
    const int C = t >> 5, G = t & 31;
    const int ct = C >> 5, r32 = C & 31;
    const int kc = G >> 2, g2 = G & 3, ks = g2 >> 1, lh = g2 & 1;
    const float* src = cb + (size_t)C * K_DIM + G * 8;
    half8 hv;
    float ss = 0.f;
#pragma unroll
    for (int j = 0; j < 8; ++j) {
      const float v = src[j];
      hv[j] = (_Float16)v;
      ss += v * v;
    }
    ss += __shfl_xor(ss, 1, 32); ss += __shfl_xor(ss, 2, 32);
    ss += __shfl_xor(ss, 4, 32); ss += __shfl_xor(ss, 8, 32);
    ss += __shfl_xor(ss, 16, 32);
    if (G == 0) en2[C] = 0.5f * ss;
    _Float16* blob = Apack + ((size_t)ct * 8 + kc) * 1024;
    const int off = ((ks * 2 + lh) * 32 + r32) * 8;
    *reinterpret_cast<half8*>(blob + off) = hv;
  } else {
    const int t = (bid - 1024) * 256 + tid;
    const int R = t >> 5, G = t & 31;
    const int rt = R >> 7, r = R & 127, jt = r >> 5, rr = r & 31;
    const int kc = G >> 2, g2 = G & 3, ks = g2 >> 1, lh = g2 & 1;
    const float* src = x + (size_t)R * K_DIM + G * 8;
    half8 hv;
#pragma unroll
    for (int j = 0; j < 8; ++j) hv[j] = (_Float16)src[j];
    _Float16* blob = Bpack + ((size_t)rt * 8 + kc) * 4096;
    const int off = ((jt * 2 + ks) * 2 + lh) * 256 + rr * 8;
    *reinterpret_cast<half8*>(blob + off) = hv;
  }
}

// ---- barrier-free h-only distance kernel (unchanged from R10) ----
__global__ __launch_bounds__(256, 2)
void vq_dist(const _Float16* __restrict__ Apack, const _Float16* __restrict__ Bpack,
             const float* __restrict__ en2, float* __restrict__ candV,
             int* __restrict__ candI, float* __restrict__ cand2) {
  __shared__ _Float16 ldsB[32768];   // 64KB

  const int tid = threadIdx.x;
  const int wv = tid >> 6, lane = tid & 63;
  const int l31 = lane & 31, lh = lane >> 5;

  const int lid = blockIdx.x;          // 0..511
  const int xcd = lid & 7, q = lid >> 3;
  const int cs = xcd >> 1;             // 0..3 (A-quarter pinned per XCD pair)
  const int bx = q * 2 + (xcd & 1);    // 0..127

  const _Float16* gB = Bpack + (size_t)bx * 32768;
#pragma unroll
  for (int s = 0; s < 16; ++s)
    GLL16(gB + (s * 256 + tid) * 8, ldsB + (s * 256 + tid) * 8);

  const int tbase = (cs * 4 + wv) * 16;
  half8 a[2][2][2];   // [parity][it][ks]
  {
    const _Float16* gA0 = Apack + ((size_t)tbase) * 8192;
#pragma unroll
    for (int it = 0; it < 2; ++it)
#pragma unroll
      for (int ks = 0; ks < 2; ++ks)
        a[0][it][ks] = *reinterpret_cast<const half8*>(
            gA0 + (size_t)it * 8192 + ((ks * 2 + lh) * 32 + l31) * 8);
  }

  asm volatile("s_waitcnt vmcnt(4)" ::: "memory");
  SCB;
  __builtin_amdgcn_s_barrier();        // only block barrier
  SCB;

  float b1[4] = {-3.0e38f, -3.0e38f, -3.0e38f, -3.0e38f};
  float b2[4] = {-3.0e38f, -3.0e38f, -3.0e38f, -3.0e38f};
  int i1[4] = {0, 0, 0, 0};

  for (int c = 0; c < 8; ++c) {
    const int t0 = tbase + c * 2;
    floatx16 acc[2][4] = {};
#pragma unroll
    for (int kc = 0; kc < 8; ++kc) {
      const int par = kc & 1, npar = par ^ 1;
      if (!(c == 7 && kc == 7)) {
        const int nt0 = (kc < 7) ? t0 : (t0 + 2);
        const int nkc = (kc < 7) ? (kc + 1) : 0;
        const _Float16* gA = Apack + ((size_t)nt0 * 8 + nkc) * 1024;
#pragma unroll
        for (int it = 0; it < 2; ++it)
#pragma unroll
          for (int ks = 0; ks < 2; ++ks)
            a[npar][it][ks] = *reinterpret_cast<const half8*>(
                gA + (size_t)it * 8192 + ((ks * 2 + lh) * 32 + l31) * 8);
      }
      SCB;
      half8 b[4][2];
#pragma unroll
      for (int jt = 0; jt < 4; ++jt)
#pragma unroll
        for (int ks = 0; ks < 2; ++ks)
          b[jt][ks] = *reinterpret_cast<const half8*>(
              ldsB + kc * 4096 + ((jt * 2 + ks) * 2 + lh) * 256 + l31 * 8);
      __builtin_amdgcn_s_setprio(1);
#pragma unroll
      for (int ks = 0; ks < 2; ++ks)
#pragma unroll
        for (int it = 0; it < 2; ++it)
#pragma unroll
          for (int jt = 0; jt < 4; ++jt)
            acc[it][jt] = MFMA16(a[par][it][ks], b[jt][ks], acc[it][jt]);
      __builtin_amdgcn_s_setprio(0);
    }

#pragma unroll
    for (int it = 0; it < 2; ++it) {
      const int code0 = (t0 + it) * 32;
      const float* ep = en2 + code0 + 4 * lh;
      const float4 e0 = *reinterpret_cast<const float4*>(ep);
      const float4 e1 = *reinterpret_cast<const float4*>(ep + 8);
      const float4 e2 = *reinterpret_cast<const float4*>(ep + 16);
      const float4 e3 = *reinterpret_cast<const float4*>(ep + 24);
      const float ev[16] = {e0.x, e0.y, e0.z, e0.w, e1.x, e1.y, e1.z, e1.w,
                            e2.x, e2.y, e2.z, e2.w, e3.x, e3.y, e3.z, e3.w};
#pragma unroll
      for (int reg = 0; reg < 16; ++reg) {
        const int code = code0 + (reg & 3) + 8 * (reg >> 2) + 4 * lh;
#pragma unroll
        for (int jt = 0; jt < 4; ++jt) {
          const float v = acc[it][jt][reg] - ev[reg];
          b2[jt] = fmaxf(b2[jt], fminf(v, b1[jt]));
          i1[jt] = (v > b1[jt]) ? code : i1[jt];
          b1[jt] = fmaxf(b1[jt], v);
        }
      }
    }
  }

#pragma unroll
  for (int jt = 0; jt < 4; ++jt) {
    const float o1 = __shfl_xor(b1[jt], 32, 64);
    const int oi = __shfl_xor(i1[jt], 32, 64);
    const float o2 = __shfl_xor(b2[jt], 32, 64);
    const float lose = fminf(b1[jt], o1);
    i1[jt] = (b1[jt] >= o1) ? i1[jt] : oi;
    b1[jt] = fmaxf(b1[jt], o1);
    b2[jt] = fmaxf(fmaxf(b2[jt], o2), lose);
  }

  if (lane < 32) {
    const int split = cs * 4 + wv;
#pragma unroll
    for (int jt = 0; jt < 4; ++jt) {
      const int row = bx * 128 + jt * 32 + l31;
      candV[(size_t)split * M_ROWS + row] = b1[jt];
      candI[(size_t)split * M_ROWS + row] = i1[jt];
      cand2[(size_t)split * M_ROWS + row] = b2[jt];
    }
  }
}

// ---- merge 16 splits -> packed key; flag risky ----
__global__ void vq_reduce(const float* __restrict__ candV, const int* __restrict__ candI,
                          const float* __restrict__ cand2, int* __restrict__ cnt,
                          int* __restrict__ risky, unsigned long long* __restrict__ key) {
  const int row = blockIdx.x * 256 + threadIdx.x;
  float b1 = candV[row];
  int i1 = candI[row];
  float b2 = cand2[row];
#pragma unroll
  for (int s = 1; s < NSPLIT; ++s) {
    const float v = candV[(size_t)s * M_ROWS + row];
    const int ii = candI[(size_t)s * M_ROWS + row];
    const float v2 = cand2[(size_t)s * M_ROWS + row];
    const float lose = fminf(b1, v);
    i1 = (v > b1) ? ii : i1;
    b1 = fmaxf(b1, v);
    b2 = fmaxf(fmaxf(b2, v2), lose);
  }
  if (b1 - b2 < TAU) {
    key[row] = 0ull;
    const int p = atomicAdd(cnt, 1);
    if (p < CAP) risky[p] = row;
  } else {
    unsigned u = __float_as_uint(b1);
    u ^= (u >> 31) ? 0xFFFFFFFFu : 0x80000000u;
    key[row] = ((unsigned long long)u << 32) | (unsigned)(N_CODES - 1 - i1);
  }
}

// ---- exact fp32 rescore v2: grid (256 code-blocks x 2 row-stripes) ----
// each thread computes ONE full (code, row) dot; cross-code max via shfl;
// cbs/xs padded to 260 (conflict-free 4-bank spread).
__global__ __launch_bounds__(256)
void vq_refine(const float* __restrict__ x, const float* __restrict__ cb,
               const float* __restrict__ en2, const int* __restrict__ cnt,
               const int* __restrict__ risky, unsigned long long* __restrict__ key) {
  __shared__ float cbs[32][260];
  __shared__ float xs[8][260];
  __shared__ int rowS[8];
  const int n0 = *cnt;
  const int n = n0 < CAP ? n0 : CAP;
  if (n == 0) return;
  const int tid = threadIdx.x;
  const int cBase = blockIdx.x * 32;
  const int cl = tid >> 3, rs = tid & 7;
#pragma unroll
  for (int q = 0; q < 32; ++q) cbs[q][tid] = cb[(size_t)(cBase + q) * K_DIM + tid];
  const float e_c = en2[cBase + cl];
  for (int t0 = blockIdx.y * 8; t0 < n; t0 += 16) {
    __syncthreads();
    if (tid < 8) {
      const int ti = t0 + tid;
      rowS[tid] = risky[ti < n ? ti : n - 1];
    }
    __syncthreads();
#pragma unroll
    for (int r = 0; r < 8; ++r) xs[r][tid] = x[(size_t)rowS[r] * K_DIM + tid];
    __syncthreads();
    float s0 = 0.f, s1 = 0.f;
#pragma unroll 4
    for (int k4 = 0; k4 < 64; k4 += 2) {
      const float4 c0 = *reinterpret_cast<const float4*>(&cbs[cl][k4 * 4]);
      const float4 x0 = *reinterpret_cast<const float4*>(&xs[rs][k4 * 4]);
      const float4 c1 = *reinterpret_cast<const float4*>(&cbs[cl][k4 * 4 + 4]);
      const float4 x1 = *reinterpret_cast<const float4*>(&xs[rs][k4 * 4 + 4]);
      s0 = fmaf(x0.x, c0.x, s0); s0 = fmaf(x0.y, c0.y, s0);
      s0 = fmaf(x0.z, c0.z, s0); s0 = fmaf(x0.w, c0.w, s0);
      s1 = fmaf(x1.x, c1.x, s1); s1 = fmaf(x1.y, c1.y, s1);
      s1 = fmaf(x1.z, c1.z, s1); s1 = fmaf(x1.w, c1.w, s1);
    }
    const float sc = (s0 + s1) - e_c;
    unsigned u = __float_as_uint(sc);
    u ^= (u >> 31) ? 0xFFFFFFFFu : 0x80000000u;
    unsigned long long k64 =
        ((unsigned long long)u << 32) | (unsigned)(N_CODES - 1 - (cBase + cl));
    // max over the wave's 8 cl values (lane bits 3,4,5)
    {
      unsigned long long o;
      o = __shfl_xor(k64, 8, 64);  if (o > k64) k64 = o;
      o = __shfl_xor(k64, 16, 64); if (o > k64) k64 = o;
      o = __shfl_xor(k64, 32, 64); if (o > k64) k64 = o;
    }
    if (((tid >> 3) & 7) == 0) atomicMax(key + rowS[rs], k64);
  }
}

// ---- gather z_q from key, write z_q_st + indices, partial loss sums ----
__global__ void vq_gather(const float* __restrict__ x, const float* __restrict__ cb,
                          const unsigned long long* __restrict__ key, float* __restrict__ zq,
                          float* __restrict__ idxf, float* __restrict__ partial) {
  __shared__ float red[256];
  const int g = blockIdx.x * 256 + threadIdx.x;
  const int row = g >> 6;
  const int c4 = g & 63;
  const int idx = N_CODES - 1 - (int)(unsigned)(key[row] & 0xFFFFFFFFull);
  if (c4 == 0) idxf[row] = (float)idx;
  const float4 z = *reinterpret_cast<const float4*>(cb + (size_t)idx * K_DIM + c4 * 4);
  const float4 xv = *reinterpret_cast<const float4*>(x + (size_t)g * 4);
  *reinterpret_cast<float4*>(zq + (size_t)g * 4) = z;
  const float dx = z.x - xv.x, dy = z.y - xv.y, dz = z.z - xv.z, dw = z.w - xv.w;
  red[threadIdx.x] = dx * dx + dy * dy + dz * dz + dw * dw;
  __syncthreads();
  for (int o = 128; o > 0; o >>= 1) {
    if (threadIdx.x < o) red[threadIdx.x] += red[threadIdx.x + o];
    __syncthreads();
  }
  if (threadIdx.x == 0) partial[blockIdx.x] = red[0];
}

__global__ void vq_loss(const float* __restrict__ partial, float* __restrict__ out) {
  __shared__ float red[256];
  float s = 0.f;
  for (int i = threadIdx.x; i < 4096; i += 256) s += partial[i];
  red[threadIdx.x] = s;
  __syncthreads();
  for (int o = 128; o > 0; o >>= 1) {
    if (threadIdx.x < o) red[threadIdx.x] += red[threadIdx.x + o];
    __syncthreads();
  }
  if (threadIdx.x == 0) out[0] = 1.25f * red[0] / 4194304.0f;
}

extern "C" void kernel_launch(void* const* d_in, const int* in_sizes, int n_in,
                              void* d_out, int out_size, void* d_ws, size_t ws_size,
                              hipStream_t stream) {
  const float* x = (const float*)d_in[0];
  const float* cb = (const float*)d_in[1];
  float* out = (float*)d_out;
  float* zq = out;
  float* loss = out + 4194304;
  float* idxf = out + 4194305;

  char* w = (char*)d_ws;
  _Float16* Apack = (_Float16*)w;                      w += (size_t)N_CODES * K_DIM * 2;   // 4MB h
  _Float16* Bpack = (_Float16*)w;                      w += (size_t)M_ROWS * K_DIM * 2;    // 8MB h
  unsigned long long* key = (unsigned long long*)w;    w += (size_t)M_ROWS * 8;
  float* en2 = (float*)w;                              w += (size_t)N_CODES * 4;
  float* candV = (float*)w;                            w += (size_t)M_ROWS * NSPLIT * 4;
  float* cand2 = (float*)w;                            w += (size_t)M_ROWS * NSPLIT * 4;
  int* candI = (int*)w;                                w += (size_t)M_ROWS * NSPLIT * 4;
  int* risky = (int*)w;                                w += (size_t)CAP * 4;
  int* cnt = (int*)w;                                  w += 64;
  float* part = (float*)w;                             w += 4096 * 4;

  pack_all<<<3072, 256, 0, stream>>>(x, cb, Apack, Bpack, en2, cnt);
  vq_dist<<<512, 256, 0, stream>>>(Apack, Bpack, en2, candV, candI, cand2);
  vq_reduce<<<M_ROWS / 256, 256, 0, stream>>>(candV, candI, cand2, cnt, risky, key);
  vq_refine<<<dim3(256, 2), 256, 0, stream>>>(x, cb, en2, cnt, risky, key);
  vq_gather<<<4194304 / (256 * 4), 256, 0, stream>>>(x, cb, key, zq, idxf, part);
  vq_loss<<<1, 256, 0, stream>>>(part, loss);
}

// Round 12
// 121.609 us; speedup vs baseline: 3.0529x; 1.8213x over previous
//
#include <hip/hip_runtime.h>

#define M_ROWS 16384
#define N_CODES 8192
#define K_DIM   256
#define NSPLIT  16
#define SCAP    16384
#define TAU     0.05f

typedef _Float16 half8 __attribute__((ext_vector_type(8)));
typedef float floatx16 __attribute__((ext_vector_type(16)));

#define GLL16(g, l) __builtin_amdgcn_global_load_lds(                         \
    (const __attribute__((address_space(1))) void*)(g),                       \
    (__attribute__((address_space(3))) void*)(l), 16, 0, 0)

#define MFMA16(a, b, c) __builtin_amdgcn_mfma_f32_32x32x16_f16(a, b, c, 0, 0, 0)
#define SCB __builtin_amdgcn_sched_barrier(0)

// ---- fused pack: codebook h-only + en2 + per-split counters zero; x h-only ----
__global__ void pack_all(const float* __restrict__ x, const float* __restrict__ cb,
                         _Float16* __restrict__ Apack, _Float16* __restrict__ Bpack,
                         float* __restrict__ en2, int* __restrict__ cntS) {
  const int bid = blockIdx.x;
  const int tid = threadIdx.x;
  if (bid == 0 && tid < NSPLIT) cntS[tid] = 0;
  if (bid < 1024) {
    const int t = bid * 256 + tid;
    const int C = t >> 5, G = t & 31;
    const int ct = C >> 5, r32 = C & 31;
    const int kc = G >> 2, g2 = G & 3, ks = g2 >> 1, lh = g2 & 1;
    const float* src = cb + (size_t)C * K_DIM + G * 8;
    half8 hv;
    float ss = 0.f;
#pragma unroll
    for (int j = 0; j < 8; ++j) {
      const float v = src[j];
      hv[j] = (_Float16)v;
      ss += v * v;
    }
    ss += __shfl_xor(ss, 1, 32); ss += __shfl_xor(ss, 2, 32);
    ss += __shfl_xor(ss, 4, 32); ss += __shfl_xor(ss, 8, 32);
    ss += __shfl_xor(ss, 16, 32);
    if (G == 0) en2[C] = 0.5f * ss;
    _Float16* blob = Apack + ((size_t)ct * 8 + kc) * 1024;
    const int off = ((ks * 2 + lh) * 32 + r32) * 8;
    *reinterpret_cast<half8*>(blob + off) = hv;
  } else {
    const int t = (bid - 1024) * 256 + tid;
    const int R = t >> 5, G = t & 31;
    const int rt = R >> 7, r = R & 127, jt = r >> 5, rr = r & 31;
    const int kc = G >> 2, g2 = G & 3, ks = g2 >> 1, lh = g2 & 1;
    const float* src = x + (size_t)R * K_DIM + G * 8;
    half8 hv;
#pragma unroll
    for (int j = 0; j < 8; ++j) hv[j] = (_Float16)src[j];
    _Float16* blob = Bpack + ((size_t)rt * 8 + kc) * 4096;
    const int off = ((jt * 2 + ks) * 2 + lh) * 256 + rr * 8;
    *reinterpret_cast<half8*>(blob + off) = hv;
  }
}

// ---- barrier-free h-only distance kernel (unchanged from R11) ----
__global__ __launch_bounds__(256, 2)
void vq_dist(const _Float16* __restrict__ Apack, const _Float16* __restrict__ Bpack,
             const float* __restrict__ en2, float* __restrict__ candV,
             int* __restrict__ candI, float* __restrict__ cand2) {
  __shared__ _Float16 ldsB[32768];   // 64KB

  const int tid = threadIdx.x;
  const int wv = tid >> 6, lane = tid & 63;
  const int l31 = lane & 31, lh = lane >> 5;

  const int lid = blockIdx.x;          // 0..511
  const int xcd = lid & 7, q = lid >> 3;
  const int cs = xcd >> 1;             // 0..3 (A-quarter pinned per XCD pair)
  const int bx = q * 2 + (xcd & 1);    // 0..127

  const _Float16* gB = Bpack + (size_t)bx * 32768;
#pragma unroll
  for (int s = 0; s < 16; ++s)
    GLL16(gB + (s * 256 + tid) * 8, ldsB + (s * 256 + tid) * 8);

  const int tbase = (cs * 4 + wv) * 16;
  half8 a[2][2][2];   // [parity][it][ks]
  {
    const _Float16* gA0 = Apack + ((size_t)tbase) * 8192;
#pragma unroll
    for (int it = 0; it < 2; ++it)
#pragma unroll
      for (int ks = 0; ks < 2; ++ks)
        a[0][it][ks] = *reinterpret_cast<const half8*>(
            gA0 + (size_t)it * 8192 + ((ks * 2 + lh) * 32 + l31) * 8);
  }

  asm volatile("s_waitcnt vmcnt(4)" ::: "memory");
  SCB;
  __builtin_amdgcn_s_barrier();        // only block barrier
  SCB;

  float b1[4] = {-3.0e38f, -3.0e38f, -3.0e38f, -3.0e38f};
  float b2[4] = {-3.0e38f, -3.0e38f, -3.0e38f, -3.0e38f};
  int i1[4] = {0, 0, 0, 0};

  for (int c = 0; c < 8; ++c) {
    const int t0 = tbase + c * 2;
    floatx16 acc[2][4] = {};
#pragma unroll
    for (int kc = 0; kc < 8; ++kc) {
      const int par = kc & 1, npar = par ^ 1;
      if (!(c == 7 && kc == 7)) {
        const int nt0 = (kc < 7) ? t0 : (t0 + 2);
        const int nkc = (kc < 7) ? (kc + 1) : 0;
        const _Float16* gA = Apack + ((size_t)nt0 * 8 + nkc) * 1024;
#pragma unroll
        for (int it = 0; it < 2; ++it)
#pragma unroll
          for (int ks = 0; ks < 2; ++ks)
            a[npar][it][ks] = *reinterpret_cast<const half8*>(
                gA + (size_t)it * 8192 + ((ks * 2 + lh) * 32 + l31) * 8);
      }
      SCB;
      half8 b[4][2];
#pragma unroll
      for (int jt = 0; jt < 4; ++jt)
#pragma unroll
        for (int ks = 0; ks < 2; ++ks)
          b[jt][ks] = *reinterpret_cast<const half8*>(
              ldsB + kc * 4096 + ((jt * 2 + ks) * 2 + lh) * 256 + l31 * 8);
      __builtin_amdgcn_s_setprio(1);
#pragma unroll
      for (int ks = 0; ks < 2; ++ks)
#pragma unroll
        for (int it = 0; it < 2; ++it)
#pragma unroll
          for (int jt = 0; jt < 4; ++jt)
            acc[it][jt] = MFMA16(a[par][it][ks], b[jt][ks], acc[it][jt]);
      __builtin_amdgcn_s_setprio(0);
    }

#pragma unroll
    for (int it = 0; it < 2; ++it) {
      const int code0 = (t0 + it) * 32;
      const float* ep = en2 + code0 + 4 * lh;
      const float4 e0 = *reinterpret_cast<const float4*>(ep);
      const float4 e1 = *reinterpret_cast<const float4*>(ep + 8);
      const float4 e2 = *reinterpret_cast<const float4*>(ep + 16);
      const float4 e3 = *reinterpret_cast<const float4*>(ep + 24);
      const float ev[16] = {e0.x, e0.y, e0.z, e0.w, e1.x, e1.y, e1.z, e1.w,
                            e2.x, e2.y, e2.z, e2.w, e3.x, e3.y, e3.z, e3.w};
#pragma unroll
      for (int reg = 0; reg < 16; ++reg) {
        const int code = code0 + (reg & 3) + 8 * (reg >> 2) + 4 * lh;
#pragma unroll
        for (int jt = 0; jt < 4; ++jt) {
          const float v = acc[it][jt][reg] - ev[reg];
          b2[jt] = fmaxf(b2[jt], fminf(v, b1[jt]));
          i1[jt] = (v > b1[jt]) ? code : i1[jt];
          b1[jt] = fmaxf(b1[jt], v);
        }
      }
    }
  }

#pragma unroll
  for (int jt = 0; jt < 4; ++jt) {
    const float o1 = __shfl_xor(b1[jt], 32, 64);
    const int oi = __shfl_xor(i1[jt], 32, 64);
    const float o2 = __shfl_xor(b2[jt], 32, 64);
    const float lose = fminf(b1[jt], o1);
    i1[jt] = (b1[jt] >= o1) ? i1[jt] : oi;
    b1[jt] = fmaxf(b1[jt], o1);
    b2[jt] = fmaxf(fmaxf(b2[jt], o2), lose);
  }

  if (lane < 32) {
    const int split = cs * 4 + wv;
#pragma unroll
    for (int jt = 0; jt < 4; ++jt) {
      const int row = bx * 128 + jt * 32 + l31;
      candV[(size_t)split * M_ROWS + row] = b1[jt];
      candI[(size_t)split * M_ROWS + row] = i1[jt];
      cand2[(size_t)split * M_ROWS + row] = b2[jt];
    }
  }
}

// ---- merge 16 splits -> packed key; enqueue risky rows onto per-split lists ----
__global__ void vq_reduce(const float* __restrict__ candV, const int* __restrict__ candI,
                          const float* __restrict__ cand2, int* __restrict__ cntS,
                          int* __restrict__ riskyS, unsigned long long* __restrict__ key) {
  const int row = blockIdx.x * 256 + threadIdx.x;
  float v[NSPLIT];
#pragma unroll
  for (int s = 0; s < NSPLIT; ++s) v[s] = candV[(size_t)s * M_ROWS + row];
  float b1 = v[0];
  int i1 = candI[row];
  float b2 = cand2[row];
#pragma unroll
  for (int s = 1; s < NSPLIT; ++s) {
    const int ii = candI[(size_t)s * M_ROWS + row];
    const float v2 = cand2[(size_t)s * M_ROWS + row];
    const float lose = fminf(b1, v[s]);
    i1 = (v[s] > b1) ? ii : i1;
    b1 = fmaxf(b1, v[s]);
    b2 = fmaxf(fmaxf(b2, v2), lose);
  }
  if (b1 - b2 < TAU) {
    key[row] = 0ull;
    const float thr = b1 - TAU;
#pragma unroll
    for (int s = 0; s < NSPLIT; ++s) {
      if (v[s] > thr) {
        const int p = atomicAdd(&cntS[s], 1);
        riskyS[(size_t)s * SCAP + p] = row;
      }
    }
  } else {
    unsigned u = __float_as_uint(b1);
    u ^= (u >> 31) ? 0xFFFFFFFFu : 0x80000000u;
    key[row] = ((unsigned long long)u << 32) | (unsigned)(N_CODES - 1 - i1);
  }
}

// ---- exact fp32 rescore, split-filtered ----
// blockIdx.x = split*16 + codeblock (32 codes); blockIdx.y = row stripe (2).
__global__ __launch_bounds__(256)
void vq_refine(const float* __restrict__ x, const float* __restrict__ cb,
               const float* __restrict__ en2, const int* __restrict__ cntS,
               const int* __restrict__ riskyS, unsigned long long* __restrict__ key) {
  __shared__ float cbs[32][260];
  __shared__ float xs[8][260];
  __shared__ int rowS[8];
  const int split = blockIdx.x >> 4;
  const int n = cntS[split];
  if (n == 0) return;
  const int tid = threadIdx.x;
  const int cBase = split * 512 + (blockIdx.x & 15) * 32;
  const int* list = riskyS + (size_t)split * SCAP;
  const int cl = tid >> 3, rs = tid & 7;
#pragma unroll
  for (int q = 0; q < 32; ++q) cbs[q][tid] = cb[(size_t)(cBase + q) * K_DIM + tid];
  const float e_c = en2[cBase + cl];
  for (int t0 = blockIdx.y * 8; t0 < n; t0 += 16) {
    __syncthreads();
    if (tid < 8) {
      const int ti = t0 + tid;
      rowS[tid] = list[ti < n ? ti : n - 1];
    }
    __syncthreads();
#pragma unroll
    for (int r = 0; r < 8; ++r) xs[r][tid] = x[(size_t)rowS[r] * K_DIM + tid];
    __syncthreads();
    float s0 = 0.f, s1 = 0.f;
#pragma unroll 4
    for (int k4 = 0; k4 < 64; k4 += 2) {
      const float4 c0 = *reinterpret_cast<const float4*>(&cbs[cl][k4 * 4]);
      const float4 x0 = *reinterpret_cast<const float4*>(&xs[rs][k4 * 4]);
      const float4 c1 = *reinterpret_cast<const float4*>(&cbs[cl][k4 * 4 + 4]);
      const float4 x1 = *reinterpret_cast<const float4*>(&xs[rs][k4 * 4 + 4]);
      s0 = fmaf(x0.x, c0.x, s0); s0 = fmaf(x0.y, c0.y, s0);
      s0 = fmaf(x0.z, c0.z, s0); s0 = fmaf(x0.w, c0.w, s0);
      s1 = fmaf(x1.x, c1.x, s1); s1 = fmaf(x1.y, c1.y, s1);
      s1 = fmaf(x1.z, c1.z, s1); s1 = fmaf(x1.w, c1.w, s1);
    }
    const float sc = (s0 + s1) - e_c;
    unsigned u = __float_as_uint(sc);
    u ^= (u >> 31) ? 0xFFFFFFFFu : 0x80000000u;
    unsigned long long k64 =
        ((unsigned long long)u << 32) | (unsigned)(N_CODES - 1 - (cBase + cl));
    {
      unsigned long long o;
      o = __shfl_xor(k64, 8, 64);  if (o > k64) k64 = o;
      o = __shfl_xor(k64, 16, 64); if (o > k64) k64 = o;
      o = __shfl_xor(k64, 32, 64); if (o > k64) k64 = o;
    }
    if (((tid >> 3) & 7) == 0) atomicMax(key + rowS[rs], k64);
  }
}

// ---- gather z_q from key, write z_q_st + indices, partial loss sums ----
__global__ void vq_gather(const float* __restrict__ x, const float* __restrict__ cb,
                          const unsigned long long* __restrict__ key, float* __restrict__ zq,
                          float* __restrict__ idxf, float* __restrict__ partial) {
  __shared__ float red[256];
  const int g = blockIdx.x * 256 + threadIdx.x;
  const int row = g >> 6;
  const int c4 = g & 63;
  const int idx = N_CODES - 1 - (int)(unsigned)(key[row] & 0xFFFFFFFFull);
  if (c4 == 0) idxf[row] = (float)idx;
  const float4 z = *reinterpret_cast<const float4*>(cb + (size_t)idx * K_DIM + c4 * 4);
  const float4 xv = *reinterpret_cast<const float4*>(x + (size_t)g * 4);
  *reinterpret_cast<float4*>(zq + (size_t)g * 4) = z;
  const float dx = z.x - xv.x, dy = z.y - xv.y, dz = z.z - xv.z, dw = z.w - xv.w;
  red[threadIdx.x] = dx * dx + dy * dy + dz * dz + dw * dw;
  __syncthreads();
  for (int o = 128; o > 0; o >>= 1) {
    if (threadIdx.x < o) red[threadIdx.x] += red[threadIdx.x + o];
    __syncthreads();
  }
  if (threadIdx.x == 0) partial[blockIdx.x] = red[0];
}

__global__ void vq_loss(const float* __restrict__ partial, float* __restrict__ out) {
  __shared__ float red[256];
  float s = 0.f;
  for (int i = threadIdx.x; i < 4096; i += 256) s += partial[i];
  red[threadIdx.x] = s;
  __syncthreads();
  for (int o = 128; o > 0; o >>= 1) {
    if (threadIdx.x < o) red[threadIdx.x] += red[threadIdx.x + o];
    __syncthreads();
  }
  if (threadIdx.x == 0) out[0] = 1.25f * red[0] / 4194304.0f;
}

extern "C" void kernel_launch(void* const* d_in, const int* in_sizes, int n_in,
                              void* d_out, int out_size, void* d_ws, size_t ws_size,
                              hipStream_t stream) {
  const float* x = (const float*)d_in[0];
  const float* cb = (const float*)d_in[1];
  float* out = (float*)d_out;
  float* zq = out;
  float* loss = out + 4194304;
  float* idxf = out + 4194305;

  char* w = (char*)d_ws;
  _Float16* Apack = (_Float16*)w;                      w += (size_t)N_CODES * K_DIM * 2;   // 4MB h
  _Float16* Bpack = (_Float16*)w;                      w += (size_t)M_ROWS * K_DIM * 2;    // 8MB h
  unsigned long long* key = (unsigned long long*)w;    w += (size_t)M_ROWS * 8;
  float* en2 = (float*)w;                              w += (size_t)N_CODES * 4;
  float* candV = (float*)w;                            w += (size_t)M_ROWS * NSPLIT * 4;
  float* cand2 = (float*)w;                            w += (size_t)M_ROWS * NSPLIT * 4;
  int* candI = (int*)w;                                w += (size_t)M_ROWS * NSPLIT * 4;
  int* riskyS = (int*)w;                               w += (size_t)NSPLIT * SCAP * 4;     // 1MB
  int* cntS = (int*)w;                                 w += 64;
  float* part = (float*)w;                             w += 4096 * 4;

  pack_all<<<3072, 256, 0, stream>>>(x, cb, Apack, Bpack, en2, cntS);
  vq_dist<<<512, 256, 0, stream>>>(Apack, Bpack, en2, candV, candI, cand2);
  vq_reduce<<<M_ROWS / 256, 256, 0, stream>>>(candV, candI, cand2, cntS, riskyS, key);
  vq_refine<<<dim3(256, 2), 256, 0, stream>>>(x, cb, en2, cntS, riskyS, key);
  vq_gather<<<4194304 / (256 * 4), 256, 0, stream>>>(x, cb, key, zq, idxf, part);
  vq_loss<<<1, 256, 0, stream>>>(part, loss);
}